// Round 3
// baseline (1323.932 us; speedup 1.0000x reference)
//
#include <hip/hip_runtime.h>
#include <stdint.h>

#define NN 100000     // N_SRC == N_TGT
#define NE 1600000
#define DD 128
#define NB ((NN + 63) / 64)   // 64-node CSR buckets -> 1563

typedef unsigned short u16;
typedef short short8 __attribute__((ext_vector_type(8)));
typedef float floatx4 __attribute__((ext_vector_type(4)));

// ===================== helpers =====================
__device__ static inline u16 f2bf(float f){
  unsigned u = __float_as_uint(f);
  unsigned r = u + 0x7FFFu + ((u >> 16) & 1u);   // RNE
  return (u16)(r >> 16);
}

// ===================== threefry2x32 (JAX-compatible) =====================
__host__ __device__ static inline unsigned rotl32(unsigned x, int r){
  return (x << r) | (x >> (32 - r));
}

__host__ __device__ static inline void tf2x32(unsigned k0, unsigned k1,
                                              unsigned c0, unsigned c1,
                                              unsigned &o0, unsigned &o1)
{
  const unsigned ks2 = k0 ^ k1 ^ 0x1BD11BDAu;
  unsigned x0 = c0 + k0, x1 = c1 + k1;
#define TFR(r) { x0 += x1; x1 = rotl32(x1, (r)); x1 ^= x0; }
  TFR(13) TFR(15) TFR(26) TFR(6)   x0 += k1;  x1 += ks2 + 1u;
  TFR(17) TFR(29) TFR(16) TFR(24)  x0 += ks2; x1 += k0 + 2u;
  TFR(13) TFR(15) TFR(26) TFR(6)   x0 += k0;  x1 += k1 + 3u;
  TFR(17) TFR(29) TFR(16) TFR(24)  x0 += k1;  x1 += ks2 + 4u;
  TFR(13) TFR(15) TFR(26) TFR(6)   x0 += ks2; x1 += k0 + 5u;
#undef TFR
  o0 = x0; o1 = x1;
}

__device__ static inline float drop_scale(unsigned k0, unsigned k1, unsigned j)
{
  unsigned o0, o1;
  tf2x32(k0, k1, 0u, j, o0, o1);
  const unsigned bits = o0 ^ o1;
  const float u = __uint_as_float((bits >> 9) | 0x3F800000u) - 1.0f;
  return (u < 0.9f) ? (1.0f / 0.9f) : 0.0f;
}

// ===================== CSR build =====================
__global__ __launch_bounds__(256) void k_count(const int* __restrict__ dst,
                                               int* __restrict__ deg){
  int i = blockIdx.x * 256 + threadIdx.x;
  if (i < NE) atomicAdd(&deg[dst[i]], 1);
}

__global__ __launch_bounds__(512) void k_scan1(const int* __restrict__ deg,
                                               int* __restrict__ part){
  __shared__ int s[512];
  int i = blockIdx.x * 512 + threadIdx.x;
  s[threadIdx.x] = (i < NN) ? deg[i] : 0;
  __syncthreads();
  for (int off = 256; off > 0; off >>= 1){
    if (threadIdx.x < off) s[threadIdx.x] += s[threadIdx.x + off];
    __syncthreads();
  }
  if (threadIdx.x == 0) part[blockIdx.x] = s[0];
}

__global__ __launch_bounds__(512) void k_scan2(int* __restrict__ part, int nb){
  __shared__ int s[512];
  const int t = threadIdx.x;
  const int v = (t < nb) ? part[t] : 0;
  s[t] = v;
  __syncthreads();
  for (int off = 1; off < 512; off <<= 1){
    int u = (t >= off) ? s[t - off] : 0;
    __syncthreads();
    s[t] += u;
    __syncthreads();
  }
  if (t < nb) part[t] = s[t] - v;   // exclusive
}

__global__ __launch_bounds__(512) void k_scan3(const int* __restrict__ deg,
                                               const int* __restrict__ part,
                                               int* __restrict__ ptr){
  __shared__ int s[512];
  int i = blockIdx.x * 512 + threadIdx.x;
  int v = (i < NN) ? deg[i] : 0;
  s[threadIdx.x] = v;
  __syncthreads();
  for (int off = 1; off < 512; off <<= 1){
    int u = (threadIdx.x >= off) ? s[threadIdx.x - off] : 0;
    __syncthreads();
    s[threadIdx.x] += u;
    __syncthreads();
  }
  int excl = s[threadIdx.x] - v + part[blockIdx.x];
  if (i < NN){
    ptr[i] = excl;
    if (i == NN - 1) ptr[NN] = excl + v;
  }
}

// bucket cursors: bcur[b] = ptr[b*64]
__global__ __launch_bounds__(256) void k_binit(const int* __restrict__ ptr,
                                               int* __restrict__ bcur){
  int i = blockIdx.x * 256 + threadIdx.x;
  if (i < NB){
    int node = i * 64; if (node > NN) node = NN;
    bcur[i] = ptr[node];
  }
}

// Pass A: scatter packed (src | dst_local<<17) into bucket-contiguous staging.
// Writes advance sequentially at NB frontiers -> near-full-line writebacks.
__global__ __launch_bounds__(256) void k_scat(const int* __restrict__ src,
                                              const int* __restrict__ dst,
                                              int* __restrict__ bcur,
                                              unsigned* __restrict__ stage){
  int i = blockIdx.x * 256 + threadIdx.x;
  if (i < NE){
    int d = dst[i];
    int pos = atomicAdd(&bcur[d >> 6], 1);
    stage[pos] = (unsigned)src[i] | ((unsigned)(d & 63) << 17);
  }
}

// Pass B: one block per bucket; exact positions via LDS counters; csr writes
// land in a contiguous ~4KB window.
__global__ __launch_bounds__(256) void k_fill2(const unsigned* __restrict__ stage,
                                               const int* __restrict__ ptr,
                                               int* __restrict__ csr){
  __shared__ int lcur[64];
  const int node0 = blockIdx.x * 64;
  const int t = threadIdx.x;
  int nend = node0 + 64; if (nend > NN) nend = NN;
  if (t < 64){
    int node = node0 + t;
    lcur[t] = (node < NN) ? ptr[node] : 0;
  }
  __syncthreads();
  const int beg = ptr[node0], end = ptr[nend];
  for (int e = beg + t; e < end; e += 256){
    unsigned p = stage[e];
    int pos = atomicAdd(&lcur[p >> 17], 1);
    csr[pos] = (int)(p & 0x1FFFFu);
  }
}

// ===================== fp32 -> bf16 convert (8 elems/thread) =================
__global__ __launch_bounds__(256) void k_cvt(const float* __restrict__ in,
                                             u16* __restrict__ out, int n8){
  int i = blockIdx.x * 256 + threadIdx.x;
  if (i >= n8) return;
  const float4* p = (const float4*)in + (size_t)i * 2;
  float4 a = p[0], b = p[1];
  u16 v[8] = { f2bf(a.x), f2bf(a.y), f2bf(a.z), f2bf(a.w),
               f2bf(b.x), f2bf(b.y), f2bf(b.z), f2bf(b.w) };
  *(uint4*)(out + (size_t)i * 8) = *(const uint4*)v;
}

// ===================== weight pre-swizzle into B-fragment order ==============
__global__ __launch_bounds__(256) void k_prepW(const float* __restrict__ Wl,
                                               const float* __restrict__ Wr,
                                               u16* __restrict__ Wsw){
  int idx = blockIdx.x * 256 + threadIdx.x;        // 0..4095
  int lane = idx & 63, tile = idx >> 6;            // tile = kt*8+nt
  int kt = tile >> 3, nt = tile & 7;
  int n = nt * 16 + (lane & 15);
  int kb = kt * 32 + (lane >> 4) * 8;
  u16 v[8];
  #pragma unroll
  for (int j = 0; j < 8; ++j){
    int k = kb + j;
    float w = (k < 128) ? Wl[(size_t)k * 128 + n] : Wr[(size_t)(k - 128) * 128 + n];
    v[j] = f2bf(w);
  }
  *(uint4*)(Wsw + (size_t)idx * 8) = *(const uint4*)v;
}

__global__ __launch_bounds__(256) void k_prepWo(const float* __restrict__ Wo,
                                                u16* __restrict__ Wsw){
  int idx = blockIdx.x * 256 + threadIdx.x;        // 0..1023
  int lane = idx & 63, tile = idx >> 6;            // tile = kt*4+nt
  int kt = tile >> 2, nt = tile & 3;
  int n = nt * 16 + (lane & 15);
  int kb = kt * 32 + (lane >> 4) * 8;
  u16 v[8];
  #pragma unroll
  for (int j = 0; j < 8; ++j)
    v[j] = f2bf(Wo[(size_t)(kb + j) * 64 + n]);
  *(uint4*)(Wsw + (size_t)idx * 8) = *(const uint4*)v;
}

// ===================== fused aggregate + layer GEMM ==========================
// Each wave: mean-aggregate its 16 A-rows into LDS (bf16, stride 136 = no
// bank conflicts on ds_read_b128), then MFMA with pre-swizzled weights.
// H = dropout(leaky_relu(concat(mean, X) @ W + b)), bf16 out.
__global__ __launch_bounds__(256) void k_aggfused(const u16* __restrict__ Xg,
    const u16* __restrict__ X, const int* __restrict__ ptr,
    const int* __restrict__ csr, const u16* __restrict__ Wsw,
    const float* __restrict__ bias, u16* __restrict__ outH,
    unsigned key0, unsigned key1)
{
  __shared__ __align__(16) u16 T[4][16][136];
  const int wave = threadIdx.x >> 6, lane = threadIdx.x & 63;
  const int quad = lane >> 4, col0 = lane & 15;
  const int row0 = blockIdx.x * 64 + wave * 16;

  // ---- phase 1: aggregate 16 rows (wave-local, no barrier needed) ----
  for (int rr = 0; rr < 16; ++rr){
    const int row = row0 + rr;
    unsigned pack = 0;
    if (row < NN){
      const int beg = ptr[row], end = ptr[row + 1];
      float a0 = 0.f, a1 = 0.f;
      int e = beg;
      for (; e + 3 < end; e += 4){
        int s0 = csr[e], s1 = csr[e + 1], s2 = csr[e + 2], s3 = csr[e + 3];
        unsigned v0 = *(const unsigned*)(Xg + (size_t)s0 * DD + lane * 2);
        unsigned v1 = *(const unsigned*)(Xg + (size_t)s1 * DD + lane * 2);
        unsigned v2 = *(const unsigned*)(Xg + (size_t)s2 * DD + lane * 2);
        unsigned v3 = *(const unsigned*)(Xg + (size_t)s3 * DD + lane * 2);
        a0 += __uint_as_float(v0 << 16) + __uint_as_float(v1 << 16)
            + __uint_as_float(v2 << 16) + __uint_as_float(v3 << 16);
        a1 += __uint_as_float(v0 & 0xFFFF0000u) + __uint_as_float(v1 & 0xFFFF0000u)
            + __uint_as_float(v2 & 0xFFFF0000u) + __uint_as_float(v3 & 0xFFFF0000u);
      }
      for (; e < end; ++e){
        unsigned v = *(const unsigned*)(Xg + (size_t)csr[e] * DD + lane * 2);
        a0 += __uint_as_float(v << 16);
        a1 += __uint_as_float(v & 0xFFFF0000u);
      }
      const int cnt = end - beg;
      const float inv = (cnt > 0) ? (1.0f / (float)cnt) : 1.0f;
      pack = (unsigned)f2bf(a0 * inv) | ((unsigned)f2bf(a1 * inv) << 16);
    }
    *(unsigned*)&T[wave][rr][lane * 2] = pack;
  }

  // ---- phase 2: MFMA ----
  int m = row0 + col0;
  if (m >= NN) m = NN - 1;

  floatx4 acc[8];
  #pragma unroll
  for (int i = 0; i < 8; ++i) acc[i] = (floatx4)0.f;

  #pragma unroll
  for (int kt = 0; kt < 8; ++kt){
    short8 a;
    if (kt < 4) a = *(const short8*)&T[wave][col0][kt * 32 + quad * 8];
    else        a = *(const short8*)(X + (size_t)m * 128 + (kt - 4) * 32 + quad * 8);
    #pragma unroll
    for (int nt = 0; nt < 8; ++nt){
      short8 b = *(const short8*)(Wsw + (size_t)(((kt * 8 + nt) * 64 + lane) * 8));
      acc[nt] = __builtin_amdgcn_mfma_f32_16x16x32_bf16(a, b, acc[nt], 0, 0, 0);
    }
  }

  // ---- epilogue: bias, leaky_relu, dropout, bf16 store ----
  #pragma unroll
  for (int nt = 0; nt < 8; ++nt){
    const int col = nt * 16 + col0;
    const float bj = bias[col];
    #pragma unroll
    for (int rg = 0; rg < 4; ++rg){
      const int r = row0 + quad * 4 + rg;
      if (r < NN){
        float h = acc[nt][rg] + bj;
        h = (h >= 0.f) ? h : 0.01f * h;
        unsigned j = (unsigned)r * 128u + (unsigned)col;
        h *= drop_scale(key0, key1, j);
        outH[(size_t)r * 128 + col] = f2bf(h);
      }
    }
  }
}

// ===================== output GEMM via MFMA (fp32 out) =======================
__global__ __launch_bounds__(256) void k_out(const u16* __restrict__ H,
    const u16* __restrict__ Wsw, const float* __restrict__ bias,
    float* __restrict__ out)
{
  const int wave = threadIdx.x >> 6, lane = threadIdx.x & 63;
  const int quad = lane >> 4, col0 = lane & 15;
  const int row0 = blockIdx.x * 64 + wave * 16;
  int m = row0 + col0;
  if (m >= NN) m = NN - 1;

  floatx4 acc[4];
  #pragma unroll
  for (int i = 0; i < 4; ++i) acc[i] = (floatx4)0.f;

  #pragma unroll
  for (int kt = 0; kt < 4; ++kt){
    short8 a = *(const short8*)(H + (size_t)m * 128 + kt * 32 + quad * 8);
    #pragma unroll
    for (int nt = 0; nt < 4; ++nt){
      short8 b = *(const short8*)(Wsw + (size_t)(((kt * 4 + nt) * 64 + lane) * 8));
      acc[nt] = __builtin_amdgcn_mfma_f32_16x16x32_bf16(a, b, acc[nt], 0, 0, 0);
    }
  }

  #pragma unroll
  for (int nt = 0; nt < 4; ++nt){
    const int col = nt * 16 + col0;
    const float bj = bias[col];
    #pragma unroll
    for (int rg = 0; rg < 4; ++rg){
      const int r = row0 + quad * 4 + rg;
      if (r < NN)
        out[(size_t)r * 64 + col] = acc[nt][rg] + bj;
    }
  }
}

// ===================== launch =====================
extern "C" void kernel_launch(void* const* d_in, const int* in_sizes, int n_in,
                              void* d_out, int out_size, void* d_ws, size_t ws_size,
                              hipStream_t stream)
{
  const float* x_src  = (const float*)d_in[0];
  const float* x_tgt  = (const float*)d_in[1];
  const float* Wl_tgt = (const float*)d_in[2];
  const float* bl_tgt = (const float*)d_in[3];
  const float* Wr_tgt = (const float*)d_in[4];
  const float* Wl_src = (const float*)d_in[5];
  const float* bl_src = (const float*)d_in[6];
  const float* Wr_src = (const float*)d_in[7];
  const float* W_o    = (const float*)d_in[8];
  const float* b_o    = (const float*)d_in[9];
  const int*   e_src  = (const int*)d_in[10];
  const int*   e_dst  = (const int*)d_in[11];
  const int*   r_src  = (const int*)d_in[12];
  const int*   r_dst  = (const int*)d_in[13];
  float* out = (float*)d_out;
  (void)in_sizes; (void)n_in; (void)out_size; (void)ws_size;

  char* ws = (char*)d_ws;
  size_t off = 0;
  auto alloc = [&](size_t bytes) -> char* {
    char* p = ws + off; off += (bytes + 255) & ~(size_t)255; return p;
  };
  u16* Xs    = (u16*)alloc((size_t)NN * DD * 2);   // bf16 x_source
  u16* Xt    = (u16*)alloc((size_t)NN * DD * 2);   // bf16 x_target
  u16* B     = (u16*)alloc((size_t)NN * DD * 2);   // h_t(l0)
  u16* C     = (u16*)alloc((size_t)NN * DD * 2);   // h_s(l0)
  u16* B2    = (u16*)alloc((size_t)NN * DD * 2);   // h_s(l1)
  u16* Wsw0  = (u16*)alloc(256 * 128 * 2);
  u16* Wsw1  = (u16*)alloc(256 * 128 * 2);
  u16* Wsw2  = (u16*)alloc(256 * 128 * 2);
  u16* Wswo  = (u16*)alloc(128 * 64 * 2);
  int* deg_t = (int*)alloc((size_t)NN * 4);
  int* deg_s = (int*)alloc((size_t)NN * 4);
  int* ptr_e = (int*)alloc((size_t)(NN + 1) * 4);
  int* ptr_r = (int*)alloc((size_t)(NN + 1) * 4);
  int* bcur  = (int*)alloc((size_t)NB * 4);
  int* csr_e = (int*)alloc((size_t)NE * 4);
  int* csr_r = (int*)alloc((size_t)NE * 4);
  unsigned* stage = (unsigned*)alloc((size_t)NE * 4);
  int* part_e = (int*)alloc(512 * 4);
  int* part_r = (int*)alloc(512 * 4);

  // dropout keys: fold_in(key(42), d) = threefry([0,42],[0,d]); d in {0,1,3}
  unsigned kt0a, kt0b, ks0a, ks0b, ks1a, ks1b;
  tf2x32(0u, 42u, 0u, 0u, kt0a, kt0b);   // layer0 new_t
  tf2x32(0u, 42u, 0u, 1u, ks0a, ks0b);   // layer0 new_s
  tf2x32(0u, 42u, 0u, 3u, ks1a, ks1b);   // layer1 new_s

  hipMemsetAsync(deg_t, 0, (size_t)NN * 4, stream);
  hipMemsetAsync(deg_s, 0, (size_t)NN * 4, stream);

  const int EB = NE / 256;                   // 6250
  const int SB = (NN + 511) / 512;           // 196
  const int CB = (NN * DD / 8 + 255) / 256;
  const int BB = (NB + 255) / 256;           // 7

  // independent prep work
  k_cvt<<<CB, 256, 0, stream>>>(x_src, Xs, NN * DD / 8);
  k_cvt<<<CB, 256, 0, stream>>>(x_tgt, Xt, NN * DD / 8);
  k_prepW<<<16, 256, 0, stream>>>(Wl_tgt, Wr_tgt, Wsw0);
  k_prepW<<<16, 256, 0, stream>>>(Wl_src, Wr_src, Wsw1);
  k_prepW<<<16, 256, 0, stream>>>(Wl_src + 128 * 128, Wr_src + 128 * 128, Wsw2);
  k_prepWo<<<4, 256, 0, stream>>>(W_o, Wswo);

  // CSR build: count -> scan -> bucketed two-pass fill
  k_count<<<EB, 256, 0, stream>>>(e_dst, deg_t);
  k_count<<<EB, 256, 0, stream>>>(r_dst, deg_s);
  k_scan1<<<SB, 512, 0, stream>>>(deg_t, part_e);
  k_scan1<<<SB, 512, 0, stream>>>(deg_s, part_r);
  k_scan2<<<1, 512, 0, stream>>>(part_e, SB);
  k_scan2<<<1, 512, 0, stream>>>(part_r, SB);
  k_scan3<<<SB, 512, 0, stream>>>(deg_t, part_e, ptr_e);
  k_scan3<<<SB, 512, 0, stream>>>(deg_s, part_r, ptr_r);

  k_binit<<<BB, 256, 0, stream>>>(ptr_e, bcur);
  k_scat<<<EB, 256, 0, stream>>>(e_src, e_dst, bcur, stage);
  k_fill2<<<NB, 256, 0, stream>>>(stage, ptr_e, csr_e);

  k_binit<<<BB, 256, 0, stream>>>(ptr_r, bcur);
  k_scat<<<EB, 256, 0, stream>>>(r_src, r_dst, bcur, stage);
  k_fill2<<<NB, 256, 0, stream>>>(stage, ptr_r, csr_r);

  const int GB = (NN + 63) / 64;    // 1563
  // layer 0, target side: new_t = f(mean(x_src), x_tgt)
  k_aggfused<<<GB, 256, 0, stream>>>(Xs, Xt, ptr_e, csr_e, Wsw0, bl_tgt, B, kt0a, kt0b);
  // layer 0, source side: new_s = f(mean(x_tgt), x_src)
  k_aggfused<<<GB, 256, 0, stream>>>(Xt, Xs, ptr_r, csr_r, Wsw1, bl_src, C, ks0a, ks0b);
  // layer 1, source side only (layer-1 target output is dead)
  k_aggfused<<<GB, 256, 0, stream>>>(B, C, ptr_r, csr_r, Wsw2, bl_src + 128, B2, ks1a, ks1b);
  // out = h_s1 @ W_out + b_out
  k_out<<<GB, 256, 0, stream>>>(B2, Wswo, b_o, out);
}

// Round 4
// 838.043 us; speedup vs baseline: 1.5798x; 1.5798x over previous
//
#include <hip/hip_runtime.h>
#include <stdint.h>

#define NN 100000     // N_SRC == N_TGT
#define NE 1600000
#define DD 128
#define XR 12500      // NN / 8 : dst range per XCD group

typedef unsigned short u16;
typedef short short8 __attribute__((ext_vector_type(8)));
typedef float floatx4 __attribute__((ext_vector_type(4)));

// ===================== helpers =====================
__device__ static inline u16 f2bf(float f){
  unsigned u = __float_as_uint(f);
  unsigned r = u + 0x7FFFu + ((u >> 16) & 1u);   // RNE
  return (u16)(r >> 16);
}

// ===================== threefry2x32 (JAX-compatible) =====================
__host__ __device__ static inline unsigned rotl32(unsigned x, int r){
  return (x << r) | (x >> (32 - r));
}

__host__ __device__ static inline void tf2x32(unsigned k0, unsigned k1,
                                              unsigned c0, unsigned c1,
                                              unsigned &o0, unsigned &o1)
{
  const unsigned ks2 = k0 ^ k1 ^ 0x1BD11BDAu;
  unsigned x0 = c0 + k0, x1 = c1 + k1;
#define TFR(r) { x0 += x1; x1 = rotl32(x1, (r)); x1 ^= x0; }
  TFR(13) TFR(15) TFR(26) TFR(6)   x0 += k1;  x1 += ks2 + 1u;
  TFR(17) TFR(29) TFR(16) TFR(24)  x0 += ks2; x1 += k0 + 2u;
  TFR(13) TFR(15) TFR(26) TFR(6)   x0 += k0;  x1 += k1 + 3u;
  TFR(17) TFR(29) TFR(16) TFR(24)  x0 += k1;  x1 += ks2 + 4u;
  TFR(13) TFR(15) TFR(26) TFR(6)   x0 += ks2; x1 += k0 + 5u;
#undef TFR
  o0 = x0; o1 = x1;
}

__device__ static inline float drop_scale(unsigned k0, unsigned k1, unsigned j)
{
  unsigned o0, o1;
  tf2x32(k0, k1, 0u, j, o0, o1);
  const unsigned bits = o0 ^ o1;
  const float u = __uint_as_float((bits >> 9) | 0x3F800000u) - 1.0f;
  return (u < 0.9f) ? (1.0f / 0.9f) : 0.0f;
}

// ===================== CSR build (XCD-partitioned by dst range) ==============
// group g = blockIdx & 7 handles dst in [g*XR,(g+1)*XR): with round-robin
// block->XCD dispatch, each deg/cur/csr line is touched by ONE XCD -> no
// cross-XCD line migration. Correct regardless of actual mapping.
__global__ __launch_bounds__(256) void k_count8(const int* __restrict__ dst,
                                                int* __restrict__ deg){
  const int g = blockIdx.x & 7;
  const int j = blockIdx.x >> 3;
  const int NJ = gridDim.x >> 3;
  const int lo = g * XR, hi = lo + XR;
  const int4* d4 = (const int4*)dst;
  for (int i = j * 256 + threadIdx.x; i < NE / 4; i += NJ * 256){
    int4 d = d4[i];
    if (d.x >= lo && d.x < hi) atomicAdd(&deg[d.x], 1);
    if (d.y >= lo && d.y < hi) atomicAdd(&deg[d.y], 1);
    if (d.z >= lo && d.z < hi) atomicAdd(&deg[d.z], 1);
    if (d.w >= lo && d.w < hi) atomicAdd(&deg[d.w], 1);
  }
}

__global__ __launch_bounds__(256) void k_fill8(const int* __restrict__ src,
                                               const int* __restrict__ dst,
                                               int* __restrict__ cur,
                                               int* __restrict__ csr){
  const int g = blockIdx.x & 7;
  const int j = blockIdx.x >> 3;
  const int NJ = gridDim.x >> 3;
  const int lo = g * XR, hi = lo + XR;
  const int4* d4 = (const int4*)dst;
  const int4* s4 = (const int4*)src;
  for (int i = j * 256 + threadIdx.x; i < NE / 4; i += NJ * 256){
    int4 d = d4[i];
    int4 s = s4[i];
    if (d.x >= lo && d.x < hi){ int p = atomicAdd(&cur[d.x], 1); csr[p] = s.x; }
    if (d.y >= lo && d.y < hi){ int p = atomicAdd(&cur[d.y], 1); csr[p] = s.y; }
    if (d.z >= lo && d.z < hi){ int p = atomicAdd(&cur[d.z], 1); csr[p] = s.z; }
    if (d.w >= lo && d.w < hi){ int p = atomicAdd(&cur[d.w], 1); csr[p] = s.w; }
  }
}

// ===================== prefix scan =====================
__global__ __launch_bounds__(512) void k_scan1(const int* __restrict__ deg,
                                               int* __restrict__ part){
  __shared__ int s[512];
  int i = blockIdx.x * 512 + threadIdx.x;
  s[threadIdx.x] = (i < NN) ? deg[i] : 0;
  __syncthreads();
  for (int off = 256; off > 0; off >>= 1){
    if (threadIdx.x < off) s[threadIdx.x] += s[threadIdx.x + off];
    __syncthreads();
  }
  if (threadIdx.x == 0) part[blockIdx.x] = s[0];
}

__global__ __launch_bounds__(512) void k_scan2(int* __restrict__ part, int nb){
  __shared__ int s[512];
  const int t = threadIdx.x;
  const int v = (t < nb) ? part[t] : 0;
  s[t] = v;
  __syncthreads();
  for (int off = 1; off < 512; off <<= 1){
    int u = (t >= off) ? s[t - off] : 0;
    __syncthreads();
    s[t] += u;
    __syncthreads();
  }
  if (t < nb) part[t] = s[t] - v;   // exclusive
}

__global__ __launch_bounds__(512) void k_scan3(const int* __restrict__ deg,
                                               const int* __restrict__ part,
                                               int* __restrict__ ptr,
                                               int* __restrict__ cur){
  __shared__ int s[512];
  int i = blockIdx.x * 512 + threadIdx.x;
  int v = (i < NN) ? deg[i] : 0;
  s[threadIdx.x] = v;
  __syncthreads();
  for (int off = 1; off < 512; off <<= 1){
    int u = (threadIdx.x >= off) ? s[threadIdx.x - off] : 0;
    __syncthreads();
    s[threadIdx.x] += u;
    __syncthreads();
  }
  int excl = s[threadIdx.x] - v + part[blockIdx.x];
  if (i < NN){
    ptr[i] = excl;
    cur[i] = excl;
    if (i == NN - 1) ptr[NN] = excl + v;
  }
}

// ===================== fp32 -> bf16 convert (8 elems/thread) =================
__global__ __launch_bounds__(256) void k_cvt(const float* __restrict__ in,
                                             u16* __restrict__ out, int n8){
  int i = blockIdx.x * 256 + threadIdx.x;
  if (i >= n8) return;
  const float4* p = (const float4*)in + (size_t)i * 2;
  float4 a = p[0], b = p[1];
  u16 v[8] = { f2bf(a.x), f2bf(a.y), f2bf(a.z), f2bf(a.w),
               f2bf(b.x), f2bf(b.y), f2bf(b.z), f2bf(b.w) };
  *(uint4*)(out + (size_t)i * 8) = *(const uint4*)v;
}

// ===================== weight pre-swizzle into B-fragment order ==============
__global__ __launch_bounds__(256) void k_prepW(const float* __restrict__ Wl,
                                               const float* __restrict__ Wr,
                                               u16* __restrict__ Wsw){
  int idx = blockIdx.x * 256 + threadIdx.x;        // 0..4095
  int lane = idx & 63, tile = idx >> 6;            // tile = kt*8+nt
  int kt = tile >> 3, nt = tile & 7;
  int n = nt * 16 + (lane & 15);
  int kb = kt * 32 + (lane >> 4) * 8;
  u16 v[8];
  #pragma unroll
  for (int j = 0; j < 8; ++j){
    int k = kb + j;
    float w = (k < 128) ? Wl[(size_t)k * 128 + n] : Wr[(size_t)(k - 128) * 128 + n];
    v[j] = f2bf(w);
  }
  *(uint4*)(Wsw + (size_t)idx * 8) = *(const uint4*)v;
}

__global__ __launch_bounds__(256) void k_prepWo(const float* __restrict__ Wo,
                                                u16* __restrict__ Wsw){
  int idx = blockIdx.x * 256 + threadIdx.x;        // 0..1023
  int lane = idx & 63, tile = idx >> 6;            // tile = kt*4+nt
  int kt = tile >> 2, nt = tile & 3;
  int n = nt * 16 + (lane & 15);
  int kb = kt * 32 + (lane >> 4) * 8;
  u16 v[8];
  #pragma unroll
  for (int j = 0; j < 8; ++j)
    v[j] = f2bf(Wo[(size_t)(kb + j) * 64 + n]);
  *(uint4*)(Wsw + (size_t)idx * 8) = *(const uint4*)v;
}

// ===================== mean aggregation (bf16 gather, 1 wave/row) ============
__global__ __launch_bounds__(256) void k_agg(const u16* __restrict__ x,
                                             const int* __restrict__ ptr,
                                             const int* __restrict__ csr,
                                             u16* __restrict__ out){
  const int row  = blockIdx.x * 4 + (threadIdx.x >> 6);
  const int lane = threadIdx.x & 63;
  const int beg = ptr[row], end = ptr[row + 1];
  float a0 = 0.f, a1 = 0.f;
  int e = beg;
  for (; e + 3 < end; e += 4){
    int s0 = csr[e], s1 = csr[e + 1], s2 = csr[e + 2], s3 = csr[e + 3];
    unsigned v0 = *(const unsigned*)(x + (size_t)s0 * DD + lane * 2);
    unsigned v1 = *(const unsigned*)(x + (size_t)s1 * DD + lane * 2);
    unsigned v2 = *(const unsigned*)(x + (size_t)s2 * DD + lane * 2);
    unsigned v3 = *(const unsigned*)(x + (size_t)s3 * DD + lane * 2);
    a0 += __uint_as_float(v0 << 16) + __uint_as_float(v1 << 16)
        + __uint_as_float(v2 << 16) + __uint_as_float(v3 << 16);
    a1 += __uint_as_float(v0 & 0xFFFF0000u) + __uint_as_float(v1 & 0xFFFF0000u)
        + __uint_as_float(v2 & 0xFFFF0000u) + __uint_as_float(v3 & 0xFFFF0000u);
  }
  for (; e < end; ++e){
    unsigned v = *(const unsigned*)(x + (size_t)csr[e] * DD + lane * 2);
    a0 += __uint_as_float(v << 16);
    a1 += __uint_as_float(v & 0xFFFF0000u);
  }
  const int cnt = end - beg;
  const float inv = (cnt > 0) ? (1.0f / (float)cnt) : 1.0f;
  unsigned pack = (unsigned)f2bf(a0 * inv) | ((unsigned)f2bf(a1 * inv) << 16);
  *(unsigned*)(out + (size_t)row * DD + lane * 2) = pack;
}

// ===================== fused layer GEMM via MFMA =============================
// H = dropout(leaky_relu(concat(Am,X) @ Wsw + b)); 4 waves/block, 16 rows/wave
__global__ __launch_bounds__(256) void k_fused(const u16* __restrict__ Am,
    const u16* __restrict__ X, const u16* __restrict__ Wsw,
    const float* __restrict__ bias, u16* __restrict__ outH,
    unsigned key0, unsigned key1)
{
  const int wave = threadIdx.x >> 6, lane = threadIdx.x & 63;
  const int quad = lane >> 4, col0 = lane & 15;
  const int row0 = blockIdx.x * 64 + wave * 16;
  int m = row0 + col0;                 // A-operand row for this lane
  if (m >= NN) m = NN - 1;             // clamp (tail block), stores guarded

  floatx4 acc[8];
  #pragma unroll
  for (int i = 0; i < 8; ++i) acc[i] = (floatx4)0.f;

  #pragma unroll
  for (int kt = 0; kt < 8; ++kt){
    const int k = kt * 32 + quad * 8;
    const u16* ap = (k < 128) ? (Am + (size_t)m * 128 + k)
                              : (X  + (size_t)m * 128 + (k - 128));
    short8 a = *(const short8*)ap;
    #pragma unroll
    for (int nt = 0; nt < 8; ++nt){
      short8 b = *(const short8*)(Wsw + (size_t)(((kt * 8 + nt) * 64 + lane) * 8));
      acc[nt] = __builtin_amdgcn_mfma_f32_16x16x32_bf16(a, b, acc[nt], 0, 0, 0);
    }
  }

  #pragma unroll
  for (int nt = 0; nt < 8; ++nt){
    const int col = nt * 16 + col0;
    const float bj = bias[col];
    #pragma unroll
    for (int rg = 0; rg < 4; ++rg){
      const int r = row0 + quad * 4 + rg;
      if (r < NN){
        float h = acc[nt][rg] + bj;
        h = (h >= 0.f) ? h : 0.01f * h;                     // leaky_relu
        unsigned j = (unsigned)r * 128u + (unsigned)col;
        h *= drop_scale(key0, key1, j);                     // dropout
        outH[(size_t)r * 128 + col] = f2bf(h);
      }
    }
  }
}

// ===================== output GEMM via MFMA (fp32 out) =======================
__global__ __launch_bounds__(256) void k_out(const u16* __restrict__ H,
    const u16* __restrict__ Wsw, const float* __restrict__ bias,
    float* __restrict__ out)
{
  const int wave = threadIdx.x >> 6, lane = threadIdx.x & 63;
  const int quad = lane >> 4, col0 = lane & 15;
  const int row0 = blockIdx.x * 64 + wave * 16;
  int m = row0 + col0;
  if (m >= NN) m = NN - 1;

  floatx4 acc[4];
  #pragma unroll
  for (int i = 0; i < 4; ++i) acc[i] = (floatx4)0.f;

  #pragma unroll
  for (int kt = 0; kt < 4; ++kt){
    short8 a = *(const short8*)(H + (size_t)m * 128 + kt * 32 + quad * 8);
    #pragma unroll
    for (int nt = 0; nt < 4; ++nt){
      short8 b = *(const short8*)(Wsw + (size_t)(((kt * 4 + nt) * 64 + lane) * 8));
      acc[nt] = __builtin_amdgcn_mfma_f32_16x16x32_bf16(a, b, acc[nt], 0, 0, 0);
    }
  }

  #pragma unroll
  for (int nt = 0; nt < 4; ++nt){
    const int col = nt * 16 + col0;
    const float bj = bias[col];
    #pragma unroll
    for (int rg = 0; rg < 4; ++rg){
      const int r = row0 + quad * 4 + rg;
      if (r < NN)
        out[(size_t)r * 64 + col] = acc[nt][rg] + bj;
    }
  }
}

// ===================== launch =====================
extern "C" void kernel_launch(void* const* d_in, const int* in_sizes, int n_in,
                              void* d_out, int out_size, void* d_ws, size_t ws_size,
                              hipStream_t stream)
{
  const float* x_src  = (const float*)d_in[0];
  const float* x_tgt  = (const float*)d_in[1];
  const float* Wl_tgt = (const float*)d_in[2];
  const float* bl_tgt = (const float*)d_in[3];
  const float* Wr_tgt = (const float*)d_in[4];
  const float* Wl_src = (const float*)d_in[5];
  const float* bl_src = (const float*)d_in[6];
  const float* Wr_src = (const float*)d_in[7];
  const float* W_o    = (const float*)d_in[8];
  const float* b_o    = (const float*)d_in[9];
  const int*   e_src  = (const int*)d_in[10];
  const int*   e_dst  = (const int*)d_in[11];
  const int*   r_src  = (const int*)d_in[12];
  const int*   r_dst  = (const int*)d_in[13];
  float* out = (float*)d_out;
  (void)in_sizes; (void)n_in; (void)out_size; (void)ws_size;

  char* ws = (char*)d_ws;
  size_t off = 0;
  auto alloc = [&](size_t bytes) -> char* {
    char* p = ws + off; off += (bytes + 255) & ~(size_t)255; return p;
  };
  u16* Xs    = (u16*)alloc((size_t)NN * DD * 2);   // bf16 x_source
  u16* Xt    = (u16*)alloc((size_t)NN * DD * 2);   // bf16 x_target
  u16* A     = (u16*)alloc((size_t)NN * DD * 2);   // agg scratch (bf16)
  u16* B     = (u16*)alloc((size_t)NN * DD * 2);   // h_t(l0), then h_s(l1)
  u16* C     = (u16*)alloc((size_t)NN * DD * 2);   // h_s(l0)
  u16* Wsw0  = (u16*)alloc(256 * 128 * 2);
  u16* Wsw1  = (u16*)alloc(256 * 128 * 2);
  u16* Wsw2  = (u16*)alloc(256 * 128 * 2);
  u16* Wswo  = (u16*)alloc(128 * 64 * 2);
  int* deg_t = (int*)alloc((size_t)NN * 4);
  int* deg_s = (int*)alloc((size_t)NN * 4);
  int* ptr_e = (int*)alloc((size_t)(NN + 1) * 4);
  int* ptr_r = (int*)alloc((size_t)(NN + 1) * 4);
  int* cur_e = (int*)alloc((size_t)NN * 4);
  int* cur_r = (int*)alloc((size_t)NN * 4);
  int* csr_e = (int*)alloc((size_t)NE * 4);
  int* csr_r = (int*)alloc((size_t)NE * 4);
  int* part_e = (int*)alloc(512 * 4);
  int* part_r = (int*)alloc(512 * 4);

  // dropout keys: fold_in(key(42), d) = threefry([0,42],[0,d]); d in {0,1,3}
  unsigned kt0a, kt0b, ks0a, ks0b, ks1a, ks1b;
  tf2x32(0u, 42u, 0u, 0u, kt0a, kt0b);   // layer0 new_t
  tf2x32(0u, 42u, 0u, 1u, ks0a, ks0b);   // layer0 new_s
  tf2x32(0u, 42u, 0u, 3u, ks1a, ks1b);   // layer1 new_s

  hipMemsetAsync(deg_t, 0, (size_t)NN * 4, stream);
  hipMemsetAsync(deg_s, 0, (size_t)NN * 4, stream);

  const int SB = (NN + 511) / 512;           // 196
  const int CB = (NN * DD / 8 + 255) / 256;
  const int PB = 8 * 256;                    // XCD-partitioned CSR grid

  // independent prep work
  k_cvt<<<CB, 256, 0, stream>>>(x_src, Xs, NN * DD / 8);
  k_cvt<<<CB, 256, 0, stream>>>(x_tgt, Xt, NN * DD / 8);
  k_prepW<<<16, 256, 0, stream>>>(Wl_tgt, Wr_tgt, Wsw0);
  k_prepW<<<16, 256, 0, stream>>>(Wl_src, Wr_src, Wsw1);
  k_prepW<<<16, 256, 0, stream>>>(Wl_src + 128 * 128, Wr_src + 128 * 128, Wsw2);
  k_prepWo<<<4, 256, 0, stream>>>(W_o, Wswo);

  // CSR build: XCD-partitioned count -> scan -> XCD-partitioned fill
  k_count8<<<PB, 256, 0, stream>>>(e_dst, deg_t);
  k_count8<<<PB, 256, 0, stream>>>(r_dst, deg_s);
  k_scan1<<<SB, 512, 0, stream>>>(deg_t, part_e);
  k_scan1<<<SB, 512, 0, stream>>>(deg_s, part_r);
  k_scan2<<<1, 512, 0, stream>>>(part_e, SB);
  k_scan2<<<1, 512, 0, stream>>>(part_r, SB);
  k_scan3<<<SB, 512, 0, stream>>>(deg_t, part_e, ptr_e, cur_e);
  k_scan3<<<SB, 512, 0, stream>>>(deg_s, part_r, ptr_r, cur_r);
  k_fill8<<<PB, 256, 0, stream>>>(e_src, e_dst, cur_e, csr_e);
  k_fill8<<<PB, 256, 0, stream>>>(r_src, r_dst, cur_r, csr_r);

  const int GB = (NN + 63) / 64;    // 1563
  const int AB = NN / 4;            // 25000
  // layer 0, target side: new_t = f(mean(x_src), x_tgt)
  k_agg<<<AB, 256, 0, stream>>>(Xs, ptr_e, csr_e, A);
  k_fused<<<GB, 256, 0, stream>>>(A, Xt, Wsw0, bl_tgt, B, kt0a, kt0b);
  // layer 0, source side: new_s = f(mean(x_tgt), x_src)
  k_agg<<<AB, 256, 0, stream>>>(Xt, ptr_r, csr_r, A);
  k_fused<<<GB, 256, 0, stream>>>(A, Xs, Wsw1, bl_src, C, ks0a, ks0b);
  // layer 1, source side only (layer-1 target output is dead)
  k_agg<<<AB, 256, 0, stream>>>(B, ptr_r, csr_r, A);
  k_fused<<<GB, 256, 0, stream>>>(A, C, Wsw2, bl_src + 128, B, ks1a, ks1b);
  // out = h_s1 @ W_out + b_out
  k_out<<<GB, 256, 0, stream>>>(B, Wswo, b_o, out);
}

// Round 5
// 810.591 us; speedup vs baseline: 1.6333x; 1.0339x over previous
//
#include <hip/hip_runtime.h>
#include <stdint.h>

#define NN 100000     // N_SRC == N_TGT
#define NE 1600000
#define DD 128
#define XR 12500      // NN / 8 : dst range per XCD group

typedef unsigned short u16;
typedef short short8 __attribute__((ext_vector_type(8)));
typedef float floatx4 __attribute__((ext_vector_type(4)));
typedef int intx4 __attribute__((ext_vector_type(4)));

// ===================== helpers =====================
__device__ static inline u16 f2bf(float f){
  unsigned u = __float_as_uint(f);
  unsigned r = u + 0x7FFFu + ((u >> 16) & 1u);   // RNE
  return (u16)(r >> 16);
}

// ===================== threefry2x32 (JAX-compatible) =====================
__host__ __device__ static inline unsigned rotl32(unsigned x, int r){
  return (x << r) | (x >> (32 - r));
}

__host__ __device__ static inline void tf2x32(unsigned k0, unsigned k1,
                                              unsigned c0, unsigned c1,
                                              unsigned &o0, unsigned &o1)
{
  const unsigned ks2 = k0 ^ k1 ^ 0x1BD11BDAu;
  unsigned x0 = c0 + k0, x1 = c1 + k1;
#define TFR(r) { x0 += x1; x1 = rotl32(x1, (r)); x1 ^= x0; }
  TFR(13) TFR(15) TFR(26) TFR(6)   x0 += k1;  x1 += ks2 + 1u;
  TFR(17) TFR(29) TFR(16) TFR(24)  x0 += ks2; x1 += k0 + 2u;
  TFR(13) TFR(15) TFR(26) TFR(6)   x0 += k0;  x1 += k1 + 3u;
  TFR(17) TFR(29) TFR(16) TFR(24)  x0 += k1;  x1 += ks2 + 4u;
  TFR(13) TFR(15) TFR(26) TFR(6)   x0 += ks2; x1 += k0 + 5u;
#undef TFR
  o0 = x0; o1 = x1;
}

__device__ static inline float drop_scale(unsigned k0, unsigned k1, unsigned j)
{
  unsigned o0, o1;
  tf2x32(k0, k1, 0u, j, o0, o1);
  const unsigned bits = o0 ^ o1;
  const float u = __uint_as_float((bits >> 9) | 0x3F800000u) - 1.0f;
  return (u < 0.9f) ? (1.0f / 0.9f) : 0.0f;
}

// ===================== CSR build =====================
// Pass 1: count degrees AND record each edge's rank within its destination
// (the atomicAdd return value). Rank fits u8 (max degree << 255 for this
// dataset: Binomial(1.6M, 1e-5), mean 16). Rank writes are coalesced u32.
__global__ __launch_bounds__(256) void k_countrank(const int* __restrict__ dst,
                                                   int* __restrict__ deg,
                                                   unsigned* __restrict__ rank){
  int i = blockIdx.x * 256 + threadIdx.x;    // indexes int4 groups
  if (i >= NE / 4) return;
  intx4 d = __builtin_nontemporal_load((const intx4*)dst + i);
  unsigned r0 = (unsigned)atomicAdd(&deg[d.x], 1) & 255u;
  unsigned r1 = (unsigned)atomicAdd(&deg[d.y], 1) & 255u;
  unsigned r2 = (unsigned)atomicAdd(&deg[d.z], 1) & 255u;
  unsigned r3 = (unsigned)atomicAdd(&deg[d.w], 1) & 255u;
  rank[i] = r0 | (r1 << 8) | (r2 << 16) | (r3 << 24);
}

// Pass 2 (after scan): atomic-free fill, XCD-partitioned by dst range so each
// csr line is written by one XCD. Streaming inputs use non-temporal loads so
// they don't evict the csr write-combining lines from L2.
__global__ __launch_bounds__(256) void k_fillr(const int* __restrict__ src,
                                               const int* __restrict__ dst,
                                               const unsigned* __restrict__ rank,
                                               const int* __restrict__ ptr,
                                               int* __restrict__ csr){
  const int g = blockIdx.x & 7;
  const int j = blockIdx.x >> 3;
  const int NJ = gridDim.x >> 3;
  const int lo = g * XR, hi = lo + XR;
  for (int i = j * 256 + threadIdx.x; i < NE / 4; i += NJ * 256){
    intx4 d = __builtin_nontemporal_load((const intx4*)dst + i);
    intx4 s = __builtin_nontemporal_load((const intx4*)src + i);
    unsigned rk = __builtin_nontemporal_load(rank + i);
    if (d.x >= lo && d.x < hi) csr[ptr[d.x] + (rk         & 255u)] = s.x;
    if (d.y >= lo && d.y < hi) csr[ptr[d.y] + ((rk >> 8)  & 255u)] = s.y;
    if (d.z >= lo && d.z < hi) csr[ptr[d.z] + ((rk >> 16) & 255u)] = s.z;
    if (d.w >= lo && d.w < hi) csr[ptr[d.w] + ((rk >> 24) & 255u)] = s.w;
  }
}

// ===================== prefix scan =====================
__global__ __launch_bounds__(512) void k_scan1(const int* __restrict__ deg,
                                               int* __restrict__ part){
  __shared__ int s[512];
  int i = blockIdx.x * 512 + threadIdx.x;
  s[threadIdx.x] = (i < NN) ? deg[i] : 0;
  __syncthreads();
  for (int off = 256; off > 0; off >>= 1){
    if (threadIdx.x < off) s[threadIdx.x] += s[threadIdx.x + off];
    __syncthreads();
  }
  if (threadIdx.x == 0) part[blockIdx.x] = s[0];
}

__global__ __launch_bounds__(512) void k_scan2(int* __restrict__ part, int nb){
  __shared__ int s[512];
  const int t = threadIdx.x;
  const int v = (t < nb) ? part[t] : 0;
  s[t] = v;
  __syncthreads();
  for (int off = 1; off < 512; off <<= 1){
    int u = (t >= off) ? s[t - off] : 0;
    __syncthreads();
    s[t] += u;
    __syncthreads();
  }
  if (t < nb) part[t] = s[t] - v;   // exclusive
}

__global__ __launch_bounds__(512) void k_scan3(const int* __restrict__ deg,
                                               const int* __restrict__ part,
                                               int* __restrict__ ptr){
  __shared__ int s[512];
  int i = blockIdx.x * 512 + threadIdx.x;
  int v = (i < NN) ? deg[i] : 0;
  s[threadIdx.x] = v;
  __syncthreads();
  for (int off = 1; off < 512; off <<= 1){
    int u = (threadIdx.x >= off) ? s[threadIdx.x - off] : 0;
    __syncthreads();
    s[threadIdx.x] += u;
    __syncthreads();
  }
  int excl = s[threadIdx.x] - v + part[blockIdx.x];
  if (i < NN){
    ptr[i] = excl;
    if (i == NN - 1) ptr[NN] = excl + v;
  }
}

// ===================== fp32 -> bf16 convert (8 elems/thread) =================
__global__ __launch_bounds__(256) void k_cvt(const float* __restrict__ in,
                                             u16* __restrict__ out, int n8){
  int i = blockIdx.x * 256 + threadIdx.x;
  if (i >= n8) return;
  floatx4 a = __builtin_nontemporal_load((const floatx4*)in + (size_t)i * 2);
  floatx4 b = __builtin_nontemporal_load((const floatx4*)in + (size_t)i * 2 + 1);
  u16 v[8] = { f2bf(a[0]), f2bf(a[1]), f2bf(a[2]), f2bf(a[3]),
               f2bf(b[0]), f2bf(b[1]), f2bf(b[2]), f2bf(b[3]) };
  *(uint4*)(out + (size_t)i * 8) = *(const uint4*)v;
}

// ===================== weight pre-swizzle into B-fragment order ==============
__global__ __launch_bounds__(256) void k_prepW(const float* __restrict__ Wl,
                                               const float* __restrict__ Wr,
                                               u16* __restrict__ Wsw){
  int idx = blockIdx.x * 256 + threadIdx.x;        // 0..4095
  int lane = idx & 63, tile = idx >> 6;            // tile = kt*8+nt
  int kt = tile >> 3, nt = tile & 7;
  int n = nt * 16 + (lane & 15);
  int kb = kt * 32 + (lane >> 4) * 8;
  u16 v[8];
  #pragma unroll
  for (int j = 0; j < 8; ++j){
    int k = kb + j;
    float w = (k < 128) ? Wl[(size_t)k * 128 + n] : Wr[(size_t)(k - 128) * 128 + n];
    v[j] = f2bf(w);
  }
  *(uint4*)(Wsw + (size_t)idx * 8) = *(const uint4*)v;
}

__global__ __launch_bounds__(256) void k_prepWo(const float* __restrict__ Wo,
                                                u16* __restrict__ Wsw){
  int idx = blockIdx.x * 256 + threadIdx.x;        // 0..1023
  int lane = idx & 63, tile = idx >> 6;            // tile = kt*4+nt
  int kt = tile >> 2, nt = tile & 3;
  int n = nt * 16 + (lane & 15);
  int kb = kt * 32 + (lane >> 4) * 8;
  u16 v[8];
  #pragma unroll
  for (int j = 0; j < 8; ++j)
    v[j] = f2bf(Wo[(size_t)(kb + j) * 64 + n]);
  *(uint4*)(Wsw + (size_t)idx * 8) = *(const uint4*)v;
}

// ===================== mean aggregation (bf16 gather, 1 wave/row) ============
__global__ __launch_bounds__(256) void k_agg(const u16* __restrict__ x,
                                             const int* __restrict__ ptr,
                                             const int* __restrict__ csr,
                                             u16* __restrict__ out){
  const int row  = blockIdx.x * 4 + (threadIdx.x >> 6);
  const int lane = threadIdx.x & 63;
  const int beg = ptr[row], end = ptr[row + 1];
  float a0 = 0.f, a1 = 0.f;
  int e = beg;
  for (; e + 7 < end; e += 8){          // 8 outstanding gathers per wave
    int sv[8];
    #pragma unroll
    for (int q = 0; q < 8; ++q) sv[q] = __builtin_nontemporal_load(csr + e + q);
    unsigned v[8];
    #pragma unroll
    for (int q = 0; q < 8; ++q)
      v[q] = *(const unsigned*)(x + (size_t)sv[q] * DD + lane * 2);
    #pragma unroll
    for (int q = 0; q < 8; ++q){
      a0 += __uint_as_float(v[q] << 16);
      a1 += __uint_as_float(v[q] & 0xFFFF0000u);
    }
  }
  for (; e < end; ++e){
    unsigned v = *(const unsigned*)(x + (size_t)__builtin_nontemporal_load(csr + e) * DD + lane * 2);
    a0 += __uint_as_float(v << 16);
    a1 += __uint_as_float(v & 0xFFFF0000u);
  }
  const int cnt = end - beg;
  const float inv = (cnt > 0) ? (1.0f / (float)cnt) : 1.0f;
  unsigned pack = (unsigned)f2bf(a0 * inv) | ((unsigned)f2bf(a1 * inv) << 16);
  *(unsigned*)(out + (size_t)row * DD + lane * 2) = pack;
}

// ===================== fused layer GEMM via MFMA =============================
// H = dropout(leaky_relu(concat(Am,X) @ Wsw + b)); 4 waves/block, 16 rows/wave
__global__ __launch_bounds__(256) void k_fused(const u16* __restrict__ Am,
    const u16* __restrict__ X, const u16* __restrict__ Wsw,
    const float* __restrict__ bias, u16* __restrict__ outH,
    unsigned key0, unsigned key1)
{
  const int wave = threadIdx.x >> 6, lane = threadIdx.x & 63;
  const int quad = lane >> 4, col0 = lane & 15;
  const int row0 = blockIdx.x * 64 + wave * 16;
  int m = row0 + col0;                 // A-operand row for this lane
  if (m >= NN) m = NN - 1;             // clamp (tail block), stores guarded

  floatx4 acc[8];
  #pragma unroll
  for (int i = 0; i < 8; ++i) acc[i] = (floatx4)0.f;

  #pragma unroll
  for (int kt = 0; kt < 8; ++kt){
    const int k = kt * 32 + quad * 8;
    const u16* ap = (k < 128) ? (Am + (size_t)m * 128 + k)
                              : (X  + (size_t)m * 128 + (k - 128));
    short8 a = __builtin_nontemporal_load((const short8*)ap);
    #pragma unroll
    for (int nt = 0; nt < 8; ++nt){
      short8 b = *(const short8*)(Wsw + (size_t)(((kt * 8 + nt) * 64 + lane) * 8));
      acc[nt] = __builtin_amdgcn_mfma_f32_16x16x32_bf16(a, b, acc[nt], 0, 0, 0);
    }
  }

  #pragma unroll
  for (int nt = 0; nt < 8; ++nt){
    const int col = nt * 16 + col0;
    const float bj = bias[col];
    #pragma unroll
    for (int rg = 0; rg < 4; ++rg){
      const int r = row0 + quad * 4 + rg;
      if (r < NN){
        float h = acc[nt][rg] + bj;
        h = (h >= 0.f) ? h : 0.01f * h;                     // leaky_relu
        unsigned j = (unsigned)r * 128u + (unsigned)col;
        h *= drop_scale(key0, key1, j);                     // dropout
        outH[(size_t)r * 128 + col] = f2bf(h);
      }
    }
  }
}

// ===================== output GEMM via MFMA (fp32 out) =======================
__global__ __launch_bounds__(256) void k_out(const u16* __restrict__ H,
    const u16* __restrict__ Wsw, const float* __restrict__ bias,
    float* __restrict__ out)
{
  const int wave = threadIdx.x >> 6, lane = threadIdx.x & 63;
  const int quad = lane >> 4, col0 = lane & 15;
  const int row0 = blockIdx.x * 64 + wave * 16;
  int m = row0 + col0;
  if (m >= NN) m = NN - 1;

  floatx4 acc[4];
  #pragma unroll
  for (int i = 0; i < 4; ++i) acc[i] = (floatx4)0.f;

  #pragma unroll
  for (int kt = 0; kt < 4; ++kt){
    short8 a = __builtin_nontemporal_load(
        (const short8*)(H + (size_t)m * 128 + kt * 32 + quad * 8));
    #pragma unroll
    for (int nt = 0; nt < 4; ++nt){
      short8 b = *(const short8*)(Wsw + (size_t)(((kt * 4 + nt) * 64 + lane) * 8));
      acc[nt] = __builtin_amdgcn_mfma_f32_16x16x32_bf16(a, b, acc[nt], 0, 0, 0);
    }
  }

  #pragma unroll
  for (int nt = 0; nt < 4; ++nt){
    const int col = nt * 16 + col0;
    const float bj = bias[col];
    #pragma unroll
    for (int rg = 0; rg < 4; ++rg){
      const int r = row0 + quad * 4 + rg;
      if (r < NN)
        out[(size_t)r * 64 + col] = acc[nt][rg] + bj;
    }
  }
}

// ===================== launch =====================
extern "C" void kernel_launch(void* const* d_in, const int* in_sizes, int n_in,
                              void* d_out, int out_size, void* d_ws, size_t ws_size,
                              hipStream_t stream)
{
  const float* x_src  = (const float*)d_in[0];
  const float* x_tgt  = (const float*)d_in[1];
  const float* Wl_tgt = (const float*)d_in[2];
  const float* bl_tgt = (const float*)d_in[3];
  const float* Wr_tgt = (const float*)d_in[4];
  const float* Wl_src = (const float*)d_in[5];
  const float* bl_src = (const float*)d_in[6];
  const float* Wr_src = (const float*)d_in[7];
  const float* W_o    = (const float*)d_in[8];
  const float* b_o    = (const float*)d_in[9];
  const int*   e_src  = (const int*)d_in[10];
  const int*   e_dst  = (const int*)d_in[11];
  const int*   r_src  = (const int*)d_in[12];
  const int*   r_dst  = (const int*)d_in[13];
  float* out = (float*)d_out;
  (void)in_sizes; (void)n_in; (void)out_size; (void)ws_size;

  char* ws = (char*)d_ws;
  size_t off = 0;
  auto alloc = [&](size_t bytes) -> char* {
    char* p = ws + off; off += (bytes + 255) & ~(size_t)255; return p;
  };
  u16* Xs    = (u16*)alloc((size_t)NN * DD * 2);   // bf16 x_source
  u16* Xt    = (u16*)alloc((size_t)NN * DD * 2);   // bf16 x_target
  u16* A     = (u16*)alloc((size_t)NN * DD * 2);   // agg scratch (bf16)
  u16* B     = (u16*)alloc((size_t)NN * DD * 2);   // h_t(l0), then h_s(l1)
  u16* C     = (u16*)alloc((size_t)NN * DD * 2);   // h_s(l0)
  u16* Wsw0  = (u16*)alloc(256 * 128 * 2);
  u16* Wsw1  = (u16*)alloc(256 * 128 * 2);
  u16* Wsw2  = (u16*)alloc(256 * 128 * 2);
  u16* Wswo  = (u16*)alloc(128 * 64 * 2);
  int* deg_t = (int*)alloc((size_t)NN * 4);
  int* deg_s = (int*)alloc((size_t)NN * 4);
  int* ptr_e = (int*)alloc((size_t)(NN + 1) * 4);
  int* ptr_r = (int*)alloc((size_t)(NN + 1) * 4);
  unsigned* rank_e = (unsigned*)alloc((size_t)(NE / 4) * 4);
  unsigned* rank_r = (unsigned*)alloc((size_t)(NE / 4) * 4);
  int* csr_e = (int*)alloc((size_t)NE * 4);
  int* csr_r = (int*)alloc((size_t)NE * 4);
  int* part_e = (int*)alloc(512 * 4);
  int* part_r = (int*)alloc(512 * 4);

  // dropout keys: fold_in(key(42), d) = threefry([0,42],[0,d]); d in {0,1,3}
  unsigned kt0a, kt0b, ks0a, ks0b, ks1a, ks1b;
  tf2x32(0u, 42u, 0u, 0u, kt0a, kt0b);   // layer0 new_t
  tf2x32(0u, 42u, 0u, 1u, ks0a, ks0b);   // layer0 new_s
  tf2x32(0u, 42u, 0u, 3u, ks1a, ks1b);   // layer1 new_s

  hipMemsetAsync(deg_t, 0, (size_t)NN * 4, stream);
  hipMemsetAsync(deg_s, 0, (size_t)NN * 4, stream);

  const int SB = (NN + 511) / 512;           // 196
  const int CB = (NN * DD / 8 + 255) / 256;
  const int QB = (NE / 4 + 255) / 256;       // 1563 : count+rank grid
  const int PB = 8 * 256;                    // XCD-partitioned fill grid

  // independent prep work
  k_cvt<<<CB, 256, 0, stream>>>(x_src, Xs, NN * DD / 8);
  k_cvt<<<CB, 256, 0, stream>>>(x_tgt, Xt, NN * DD / 8);
  k_prepW<<<16, 256, 0, stream>>>(Wl_tgt, Wr_tgt, Wsw0);
  k_prepW<<<16, 256, 0, stream>>>(Wl_src, Wr_src, Wsw1);
  k_prepW<<<16, 256, 0, stream>>>(Wl_src + 128 * 128, Wr_src + 128 * 128, Wsw2);
  k_prepWo<<<4, 256, 0, stream>>>(W_o, Wswo);

  // CSR build: count+rank -> scan -> atomic-free partitioned fill
  k_countrank<<<QB, 256, 0, stream>>>(e_dst, deg_t, rank_e);
  k_countrank<<<QB, 256, 0, stream>>>(r_dst, deg_s, rank_r);
  k_scan1<<<SB, 512, 0, stream>>>(deg_t, part_e);
  k_scan1<<<SB, 512, 0, stream>>>(deg_s, part_r);
  k_scan2<<<1, 512, 0, stream>>>(part_e, SB);
  k_scan2<<<1, 512, 0, stream>>>(part_r, SB);
  k_scan3<<<SB, 512, 0, stream>>>(deg_t, part_e, ptr_e);
  k_scan3<<<SB, 512, 0, stream>>>(deg_s, part_r, ptr_r);
  k_fillr<<<PB, 256, 0, stream>>>(e_src, e_dst, rank_e, ptr_e, csr_e);
  k_fillr<<<PB, 256, 0, stream>>>(r_src, r_dst, rank_r, ptr_r, csr_r);

  const int GB = (NN + 63) / 64;    // 1563
  const int AB = NN / 4;            // 25000
  // layer 0, target side: new_t = f(mean(x_src), x_tgt)
  k_agg<<<AB, 256, 0, stream>>>(Xs, ptr_e, csr_e, A);
  k_fused<<<GB, 256, 0, stream>>>(A, Xt, Wsw0, bl_tgt, B, kt0a, kt0b);
  // layer 0, source side: new_s = f(mean(x_tgt), x_src)
  k_agg<<<AB, 256, 0, stream>>>(Xt, ptr_r, csr_r, A);
  k_fused<<<GB, 256, 0, stream>>>(A, Xs, Wsw1, bl_src, C, ks0a, ks0b);
  // layer 1, source side only (layer-1 target output is dead)
  k_agg<<<AB, 256, 0, stream>>>(B, ptr_r, csr_r, A);
  k_fused<<<GB, 256, 0, stream>>>(A, C, Wsw2, bl_src + 128, B, ks1a, ks1b);
  // out = h_s1 @ W_out + b_out
  k_out<<<GB, 256, 0, stream>>>(B, Wswo, b_o, out);
}

// Round 6
// 676.782 us; speedup vs baseline: 1.9562x; 1.1977x over previous
//
#include <hip/hip_runtime.h>
#include <stdint.h>

#define NN 100000     // N_SRC == N_TGT
#define NE 1600000
#define DD 128
#define XR 12500      // NN / 8 : dst range per XCD group
#define PS 48         // padded CSR slots per node (deg: mean 16, P(>=48)~1e-9)

typedef unsigned short u16;
typedef short short8 __attribute__((ext_vector_type(8)));
typedef float floatx4 __attribute__((ext_vector_type(4)));
typedef int intx4 __attribute__((ext_vector_type(4)));

// ===================== helpers =====================
__device__ static inline u16 f2bf(float f){
  unsigned u = __float_as_uint(f);
  unsigned r = u + 0x7FFFu + ((u >> 16) & 1u);   // RNE
  return (u16)(r >> 16);
}

// ===================== threefry2x32 (JAX-compatible) =====================
__host__ __device__ static inline unsigned rotl32(unsigned x, int r){
  return (x << r) | (x >> (32 - r));
}

__host__ __device__ static inline void tf2x32(unsigned k0, unsigned k1,
                                              unsigned c0, unsigned c1,
                                              unsigned &o0, unsigned &o1)
{
  const unsigned ks2 = k0 ^ k1 ^ 0x1BD11BDAu;
  unsigned x0 = c0 + k0, x1 = c1 + k1;
#define TFR(r) { x0 += x1; x1 = rotl32(x1, (r)); x1 ^= x0; }
  TFR(13) TFR(15) TFR(26) TFR(6)   x0 += k1;  x1 += ks2 + 1u;
  TFR(17) TFR(29) TFR(16) TFR(24)  x0 += ks2; x1 += k0 + 2u;
  TFR(13) TFR(15) TFR(26) TFR(6)   x0 += k0;  x1 += k1 + 3u;
  TFR(17) TFR(29) TFR(16) TFR(24)  x0 += k1;  x1 += ks2 + 4u;
  TFR(13) TFR(15) TFR(26) TFR(6)   x0 += ks2; x1 += k0 + 5u;
#undef TFR
  o0 = x0; o1 = x1;
}

__device__ static inline float drop_scale(unsigned k0, unsigned k1, unsigned j)
{
  unsigned o0, o1;
  tf2x32(k0, k1, 0u, j, o0, o1);
  const unsigned bits = o0 ^ o1;
  const float u = __uint_as_float((bits >> 9) | 0x3F800000u) - 1.0f;
  return (u < 0.9f) ? (1.0f / 0.9f) : 0.0f;
}

// ===================== padded-CSR single-pass build =======================
// Fixed 48-slot row per node: csr[dst*48 + rank], rank from XCD-local atomic.
// Group g = blockIdx&7 owns dst range [g*XR,(g+1)*XR): its deg counters AND
// its 2.4 MB csr slice stay in one XCD's L2 -> dirty lines written back once.
// Edge streams use non-temporal loads so they don't evict the csr slice.
__global__ __launch_bounds__(256) void k_fillp(const int* __restrict__ src,
                                               const int* __restrict__ dst,
                                               int* __restrict__ deg,
                                               int* __restrict__ csr){
  const int g = blockIdx.x & 7;
  const int j = blockIdx.x >> 3;
  const int NJ = gridDim.x >> 3;
  const int lo = g * XR, hi = lo + XR;
  for (int i = j * 256 + threadIdx.x; i < NE / 4; i += NJ * 256){
    intx4 d = __builtin_nontemporal_load((const intx4*)dst + i);
    intx4 s = __builtin_nontemporal_load((const intx4*)src + i);
    if (d.x >= lo && d.x < hi){ int p = atomicAdd(&deg[d.x], 1); if (p < PS) csr[d.x * PS + p] = s.x; }
    if (d.y >= lo && d.y < hi){ int p = atomicAdd(&deg[d.y], 1); if (p < PS) csr[d.y * PS + p] = s.y; }
    if (d.z >= lo && d.z < hi){ int p = atomicAdd(&deg[d.z], 1); if (p < PS) csr[d.z * PS + p] = s.z; }
    if (d.w >= lo && d.w < hi){ int p = atomicAdd(&deg[d.w], 1); if (p < PS) csr[d.w * PS + p] = s.w; }
  }
}

// ===================== fp32 -> bf16 convert (8 elems/thread) =================
__global__ __launch_bounds__(256) void k_cvt(const float* __restrict__ in,
                                             u16* __restrict__ out, int n8){
  int i = blockIdx.x * 256 + threadIdx.x;
  if (i >= n8) return;
  floatx4 a = __builtin_nontemporal_load((const floatx4*)in + (size_t)i * 2);
  floatx4 b = __builtin_nontemporal_load((const floatx4*)in + (size_t)i * 2 + 1);
  u16 v[8] = { f2bf(a[0]), f2bf(a[1]), f2bf(a[2]), f2bf(a[3]),
               f2bf(b[0]), f2bf(b[1]), f2bf(b[2]), f2bf(b[3]) };
  *(uint4*)(out + (size_t)i * 8) = *(const uint4*)v;
}

// ===================== weight pre-swizzle into B-fragment order ==============
__global__ __launch_bounds__(256) void k_prepW(const float* __restrict__ Wl,
                                               const float* __restrict__ Wr,
                                               u16* __restrict__ Wsw){
  int idx = blockIdx.x * 256 + threadIdx.x;        // 0..4095
  int lane = idx & 63, tile = idx >> 6;            // tile = kt*8+nt
  int kt = tile >> 3, nt = tile & 7;
  int n = nt * 16 + (lane & 15);
  int kb = kt * 32 + (lane >> 4) * 8;
  u16 v[8];
  #pragma unroll
  for (int j = 0; j < 8; ++j){
    int k = kb + j;
    float w = (k < 128) ? Wl[(size_t)k * 128 + n] : Wr[(size_t)(k - 128) * 128 + n];
    v[j] = f2bf(w);
  }
  *(uint4*)(Wsw + (size_t)idx * 8) = *(const uint4*)v;
}

__global__ __launch_bounds__(256) void k_prepWo(const float* __restrict__ Wo,
                                                u16* __restrict__ Wsw){
  int idx = blockIdx.x * 256 + threadIdx.x;        // 0..1023
  int lane = idx & 63, tile = idx >> 6;            // tile = kt*4+nt
  int kt = tile >> 2, nt = tile & 3;
  int n = nt * 16 + (lane & 15);
  int kb = kt * 32 + (lane >> 4) * 8;
  u16 v[8];
  #pragma unroll
  for (int j = 0; j < 8; ++j)
    v[j] = f2bf(Wo[(size_t)(kb + j) * 64 + n]);
  *(uint4*)(Wsw + (size_t)idx * 8) = *(const uint4*)v;
}

// ===================== mean aggregation ======================================
// 1 wave/row; 2 edges per gather instruction: lanes 0-31 = even edge, lanes
// 32-63 = odd edge, each lane covers 4 channels (dwordx2). Halves combined at
// the end with one shfl_xor(32).
__global__ __launch_bounds__(256) void k_agg(const u16* __restrict__ x,
                                             const int* __restrict__ deg,
                                             const int* __restrict__ csr,
                                             u16* __restrict__ out){
  const int row  = blockIdx.x * 4 + (threadIdx.x >> 6);
  const int lane = threadIdx.x & 63;
  const int half = lane >> 5, l5 = lane & 31;
  int cnt = deg[row];
  if (cnt > PS) cnt = PS;
  const int beg = row * PS;
  float a0 = 0.f, a1 = 0.f, a2 = 0.f, a3 = 0.f;
  int e = 0;
  for (; e + 7 < cnt; e += 8){
    #pragma unroll
    for (int q = 0; q < 4; ++q){
      int s0 = csr[beg + e + 2 * q];
      int s1 = csr[beg + e + 2 * q + 1];
      int sm = half ? s1 : s0;
      uint2 v = *(const uint2*)(x + (size_t)sm * DD + l5 * 4);
      a0 += __uint_as_float(v.x << 16);
      a1 += __uint_as_float(v.x & 0xFFFF0000u);
      a2 += __uint_as_float(v.y << 16);
      a3 += __uint_as_float(v.y & 0xFFFF0000u);
    }
  }
  for (; e + 1 < cnt; e += 2){
    int s0 = csr[beg + e];
    int s1 = csr[beg + e + 1];
    int sm = half ? s1 : s0;
    uint2 v = *(const uint2*)(x + (size_t)sm * DD + l5 * 4);
    a0 += __uint_as_float(v.x << 16);
    a1 += __uint_as_float(v.x & 0xFFFF0000u);
    a2 += __uint_as_float(v.y << 16);
    a3 += __uint_as_float(v.y & 0xFFFF0000u);
  }
  if (e < cnt && half == 0){               // odd tail edge: half0 only
    int sm = csr[beg + e];
    uint2 v = *(const uint2*)(x + (size_t)sm * DD + l5 * 4);
    a0 += __uint_as_float(v.x << 16);
    a1 += __uint_as_float(v.x & 0xFFFF0000u);
    a2 += __uint_as_float(v.y << 16);
    a3 += __uint_as_float(v.y & 0xFFFF0000u);
  }
  a0 += __shfl_xor(a0, 32);
  a1 += __shfl_xor(a1, 32);
  a2 += __shfl_xor(a2, 32);
  a3 += __shfl_xor(a3, 32);
  const float inv = (cnt > 0) ? (1.0f / (float)cnt) : 1.0f;
  if (half == 0){
    uint2 p;
    p.x = (unsigned)f2bf(a0 * inv) | ((unsigned)f2bf(a1 * inv) << 16);
    p.y = (unsigned)f2bf(a2 * inv) | ((unsigned)f2bf(a3 * inv) << 16);
    *(uint2*)(out + (size_t)row * DD + l5 * 4) = p;
  }
}

// ===================== fused layer GEMM via MFMA =============================
// H = dropout(leaky_relu(concat(Am,X) @ Wsw + b)); 4 waves/block, 16 rows/wave
__global__ __launch_bounds__(256) void k_fused(const u16* __restrict__ Am,
    const u16* __restrict__ X, const u16* __restrict__ Wsw,
    const float* __restrict__ bias, u16* __restrict__ outH,
    unsigned key0, unsigned key1)
{
  const int wave = threadIdx.x >> 6, lane = threadIdx.x & 63;
  const int quad = lane >> 4, col0 = lane & 15;
  const int row0 = blockIdx.x * 64 + wave * 16;
  int m = row0 + col0;                 // A-operand row for this lane
  if (m >= NN) m = NN - 1;             // clamp (tail block), stores guarded

  floatx4 acc[8];
  #pragma unroll
  for (int i = 0; i < 8; ++i) acc[i] = (floatx4)0.f;

  #pragma unroll
  for (int kt = 0; kt < 8; ++kt){
    const int k = kt * 32 + quad * 8;
    const u16* ap = (k < 128) ? (Am + (size_t)m * 128 + k)
                              : (X  + (size_t)m * 128 + (k - 128));
    short8 a = __builtin_nontemporal_load((const short8*)ap);
    #pragma unroll
    for (int nt = 0; nt < 8; ++nt){
      short8 b = *(const short8*)(Wsw + (size_t)(((kt * 8 + nt) * 64 + lane) * 8));
      acc[nt] = __builtin_amdgcn_mfma_f32_16x16x32_bf16(a, b, acc[nt], 0, 0, 0);
    }
  }

  #pragma unroll
  for (int nt = 0; nt < 8; ++nt){
    const int col = nt * 16 + col0;
    const float bj = bias[col];
    #pragma unroll
    for (int rg = 0; rg < 4; ++rg){
      const int r = row0 + quad * 4 + rg;
      if (r < NN){
        float h = acc[nt][rg] + bj;
        h = (h >= 0.f) ? h : 0.01f * h;                     // leaky_relu
        unsigned j = (unsigned)r * 128u + (unsigned)col;
        h *= drop_scale(key0, key1, j);                     // dropout
        outH[(size_t)r * 128 + col] = f2bf(h);
      }
    }
  }
}

// ===================== output GEMM via MFMA (fp32 out) =======================
__global__ __launch_bounds__(256) void k_out(const u16* __restrict__ H,
    const u16* __restrict__ Wsw, const float* __restrict__ bias,
    float* __restrict__ out)
{
  const int wave = threadIdx.x >> 6, lane = threadIdx.x & 63;
  const int quad = lane >> 4, col0 = lane & 15;
  const int row0 = blockIdx.x * 64 + wave * 16;
  int m = row0 + col0;
  if (m >= NN) m = NN - 1;

  floatx4 acc[4];
  #pragma unroll
  for (int i = 0; i < 4; ++i) acc[i] = (floatx4)0.f;

  #pragma unroll
  for (int kt = 0; kt < 4; ++kt){
    short8 a = __builtin_nontemporal_load(
        (const short8*)(H + (size_t)m * 128 + kt * 32 + quad * 8));
    #pragma unroll
    for (int nt = 0; nt < 4; ++nt){
      short8 b = *(const short8*)(Wsw + (size_t)(((kt * 4 + nt) * 64 + lane) * 8));
      acc[nt] = __builtin_amdgcn_mfma_f32_16x16x32_bf16(a, b, acc[nt], 0, 0, 0);
    }
  }

  #pragma unroll
  for (int nt = 0; nt < 4; ++nt){
    const int col = nt * 16 + col0;
    const float bj = bias[col];
    #pragma unroll
    for (int rg = 0; rg < 4; ++rg){
      const int r = row0 + quad * 4 + rg;
      if (r < NN)
        out[(size_t)r * 64 + col] = acc[nt][rg] + bj;
    }
  }
}

// ===================== launch =====================
extern "C" void kernel_launch(void* const* d_in, const int* in_sizes, int n_in,
                              void* d_out, int out_size, void* d_ws, size_t ws_size,
                              hipStream_t stream)
{
  const float* x_src  = (const float*)d_in[0];
  const float* x_tgt  = (const float*)d_in[1];
  const float* Wl_tgt = (const float*)d_in[2];
  const float* bl_tgt = (const float*)d_in[3];
  const float* Wr_tgt = (const float*)d_in[4];
  const float* Wl_src = (const float*)d_in[5];
  const float* bl_src = (const float*)d_in[6];
  const float* Wr_src = (const float*)d_in[7];
  const float* W_o    = (const float*)d_in[8];
  const float* b_o    = (const float*)d_in[9];
  const int*   e_src  = (const int*)d_in[10];
  const int*   e_dst  = (const int*)d_in[11];
  const int*   r_src  = (const int*)d_in[12];
  const int*   r_dst  = (const int*)d_in[13];
  float* out = (float*)d_out;
  (void)in_sizes; (void)n_in; (void)out_size; (void)ws_size;

  char* ws = (char*)d_ws;
  size_t off = 0;
  auto alloc = [&](size_t bytes) -> char* {
    char* p = ws + off; off += (bytes + 255) & ~(size_t)255; return p;
  };
  u16* Xs    = (u16*)alloc((size_t)NN * DD * 2);   // bf16 x_source
  u16* Xt    = (u16*)alloc((size_t)NN * DD * 2);   // bf16 x_target
  u16* A     = (u16*)alloc((size_t)NN * DD * 2);   // agg scratch (bf16)
  u16* B     = (u16*)alloc((size_t)NN * DD * 2);   // h_t(l0), then h_s(l1)
  u16* C     = (u16*)alloc((size_t)NN * DD * 2);   // h_s(l0)
  u16* Wsw0  = (u16*)alloc(256 * 128 * 2);
  u16* Wsw1  = (u16*)alloc(256 * 128 * 2);
  u16* Wsw2  = (u16*)alloc(256 * 128 * 2);
  u16* Wswo  = (u16*)alloc(128 * 64 * 2);
  int* deg_t = (int*)alloc((size_t)NN * 4);
  int* deg_s = (int*)alloc((size_t)NN * 4);
  int* csr_e = (int*)alloc((size_t)NN * PS * 4);   // padded CSR (19.2 MB)
  int* csr_r = (int*)alloc((size_t)NN * PS * 4);

  // dropout keys: fold_in(key(42), d) = threefry([0,42],[0,d]); d in {0,1,3}
  unsigned kt0a, kt0b, ks0a, ks0b, ks1a, ks1b;
  tf2x32(0u, 42u, 0u, 0u, kt0a, kt0b);   // layer0 new_t
  tf2x32(0u, 42u, 0u, 1u, ks0a, ks0b);   // layer0 new_s
  tf2x32(0u, 42u, 0u, 3u, ks1a, ks1b);   // layer1 new_s

  hipMemsetAsync(deg_t, 0, (size_t)NN * 4, stream);
  hipMemsetAsync(deg_s, 0, (size_t)NN * 4, stream);

  const int CB = (NN * DD / 8 + 255) / 256;
  const int PB = 8 * 256;                    // XCD-partitioned fill grid

  // independent prep work
  k_cvt<<<CB, 256, 0, stream>>>(x_src, Xs, NN * DD / 8);
  k_cvt<<<CB, 256, 0, stream>>>(x_tgt, Xt, NN * DD / 8);
  k_prepW<<<16, 256, 0, stream>>>(Wl_tgt, Wr_tgt, Wsw0);
  k_prepW<<<16, 256, 0, stream>>>(Wl_src, Wr_src, Wsw1);
  k_prepW<<<16, 256, 0, stream>>>(Wl_src + 128 * 128, Wr_src + 128 * 128, Wsw2);
  k_prepWo<<<4, 256, 0, stream>>>(W_o, Wswo);

  // padded CSR build: one pass per direction
  k_fillp<<<PB, 256, 0, stream>>>(e_src, e_dst, deg_t, csr_e);
  k_fillp<<<PB, 256, 0, stream>>>(r_src, r_dst, deg_s, csr_r);

  const int GB = (NN + 63) / 64;    // 1563
  const int AB = NN / 4;            // 25000
  // layer 0, target side: new_t = f(mean(x_src), x_tgt)
  k_agg<<<AB, 256, 0, stream>>>(Xs, deg_t, csr_e, A);
  k_fused<<<GB, 256, 0, stream>>>(A, Xt, Wsw0, bl_tgt, B, kt0a, kt0b);
  // layer 0, source side: new_s = f(mean(x_tgt), x_src)
  k_agg<<<AB, 256, 0, stream>>>(Xt, deg_s, csr_r, A);
  k_fused<<<GB, 256, 0, stream>>>(A, Xs, Wsw1, bl_src, C, ks0a, ks0b);
  // layer 1, source side only (layer-1 target output is dead)
  k_agg<<<AB, 256, 0, stream>>>(B, deg_s, csr_r, A);
  k_fused<<<GB, 256, 0, stream>>>(A, C, Wsw2, bl_src + 128, B, ks1a, ks1b);
  // out = h_s1 @ W_out + b_out
  k_out<<<GB, 256, 0, stream>>>(B, Wswo, b_o, out);
}

// Round 7
// 657.074 us; speedup vs baseline: 2.0149x; 1.0300x over previous
//
#include <hip/hip_runtime.h>
#include <stdint.h>

#define NN 100000     // N_SRC == N_TGT
#define NE 1600000
#define DD 128
#define XR 12500      // NN / 8 : dst range per XCD group
#define PS 48         // padded CSR slots per node (deg: mean 16, max ~40)
#define HB 1024       // hist/scatter blocks

typedef unsigned short u16;
typedef short short8 __attribute__((ext_vector_type(8)));
typedef float floatx4 __attribute__((ext_vector_type(4)));
typedef int intx4 __attribute__((ext_vector_type(4)));

// ===================== helpers =====================
__device__ static inline u16 f2bf(float f){
  unsigned u = __float_as_uint(f);
  unsigned r = u + 0x7FFFu + ((u >> 16) & 1u);   // RNE
  return (u16)(r >> 16);
}

// ===================== threefry2x32 (JAX-compatible) =====================
__host__ __device__ static inline unsigned rotl32(unsigned x, int r){
  return (x << r) | (x >> (32 - r));
}

__host__ __device__ static inline void tf2x32(unsigned k0, unsigned k1,
                                              unsigned c0, unsigned c1,
                                              unsigned &o0, unsigned &o1)
{
  const unsigned ks2 = k0 ^ k1 ^ 0x1BD11BDAu;
  unsigned x0 = c0 + k0, x1 = c1 + k1;
#define TFR(r) { x0 += x1; x1 = rotl32(x1, (r)); x1 ^= x0; }
  TFR(13) TFR(15) TFR(26) TFR(6)   x0 += k1;  x1 += ks2 + 1u;
  TFR(17) TFR(29) TFR(16) TFR(24)  x0 += ks2; x1 += k0 + 2u;
  TFR(13) TFR(15) TFR(26) TFR(6)   x0 += k0;  x1 += k1 + 3u;
  TFR(17) TFR(29) TFR(16) TFR(24)  x0 += k1;  x1 += ks2 + 4u;
  TFR(13) TFR(15) TFR(26) TFR(6)   x0 += ks2; x1 += k0 + 5u;
#undef TFR
  o0 = x0; o1 = x1;
}

__device__ static inline float drop_scale(unsigned k0, unsigned k1, unsigned j)
{
  unsigned o0, o1;
  tf2x32(k0, k1, 0u, j, o0, o1);
  const unsigned bits = o0 ^ o1;
  const float u = __uint_as_float((bits >> 9) | 0x3F800000u) - 1.0f;
  return (u < 0.9f) ? (1.0f / 0.9f) : 0.0f;
}

// ===================== edge partition: hist -> scan -> scatter ===============
// 16 buckets = direction (e/r) x 8 dst ranges. hist[b*HB + blk] = count of
// bucket-b edges seen by block blk. Same grid-stride mapping in hist & scatter.
__global__ __launch_bounds__(256) void k_hist(const int* __restrict__ e_dst,
                                              const int* __restrict__ r_dst,
                                              int* __restrict__ hist){
  __shared__ int h[16];
  const int t = threadIdx.x;
  if (t < 16) h[t] = 0;
  __syncthreads();
  const int QT = 2 * (NE / 4);
  for (int i = blockIdx.x * 256 + t; i < QT; i += HB * 256){
    int dir = (i >= NE / 4);
    int qi = dir ? i - NE / 4 : i;
    const int* dp = dir ? r_dst : e_dst;
    intx4 d = __builtin_nontemporal_load((const intx4*)dp + qi);
    int bb = dir << 3;
    atomicAdd(&h[bb + d.x / XR], 1);
    atomicAdd(&h[bb + d.y / XR], 1);
    atomicAdd(&h[bb + d.z / XR], 1);
    atomicAdd(&h[bb + d.w / XR], 1);
  }
  __syncthreads();
  if (t < 16) hist[t * HB + blockIdx.x] = h[t];
}

// Exclusive scan over hist[16*HB] (bucket-major); hist[16*HB] = total.
// Per-thread elements are a stride-16 comb WITHIN one bucket (bank-friendly);
// any within-bucket permutation yields valid disjoint block ranges.
__global__ __launch_bounds__(256) void k_scan(int* __restrict__ hist){
  __shared__ int sh[16 * HB];
  __shared__ int tot[256];
  const int t = threadIdx.x;
  const int N = 16 * HB;
  for (int k = t; k < N; k += 256) sh[k] = hist[k];
  __syncthreads();
  // element index for (t, k): bucket = t>>4, comb offset = (t&15) + 16k
  int s = 0;
  #pragma unroll 4
  for (int k = 0; k < 64; ++k)
    s += sh[(t >> 4) * HB + (t & 15) + (k << 4)];
  tot[t] = s;
  __syncthreads();
  int v = s;
  for (int off = 1; off < 256; off <<= 1){
    int u = (t >= off) ? tot[t - off] : 0;
    __syncthreads();
    tot[t] += u;
    __syncthreads();
  }
  int run = tot[t] - v;     // exclusive base of this thread's comb
  for (int k = 0; k < 64; ++k){
    int idx = (t >> 4) * HB + (t & 15) + (k << 4);
    int xv = sh[idx];
    sh[idx] = run;
    run += xv;
  }
  __syncthreads();
  for (int k = t; k < N; k += 256) hist[k] = sh[k];
  if (t == 255) hist[N] = tot[255];   // grand total = 2*NE
}

// Scatter edges into bucket-contiguous staging; positions from scanned hist,
// so no global atomic hotspots. Record = (dst_local<<17) | src  (14+17 bits).
__global__ __launch_bounds__(256) void k_scatter(const int* __restrict__ e_src,
                                                 const int* __restrict__ e_dst,
                                                 const int* __restrict__ r_src,
                                                 const int* __restrict__ r_dst,
                                                 const int* __restrict__ base,
                                                 unsigned* __restrict__ stage){
  __shared__ int cur[16];
  const int t = threadIdx.x;
  if (t < 16) cur[t] = base[t * HB + blockIdx.x];
  __syncthreads();
  const int QT = 2 * (NE / 4);
  for (int i = blockIdx.x * 256 + t; i < QT; i += HB * 256){
    int dir = (i >= NE / 4);
    int qi = dir ? i - NE / 4 : i;
    const int* dp = dir ? r_dst : e_dst;
    const int* sp = dir ? r_src : e_src;
    intx4 d = __builtin_nontemporal_load((const intx4*)dp + qi);
    intx4 sv = __builtin_nontemporal_load((const intx4*)sp + qi);
    int bb = dir << 3;
    int g, p;
    g = d.x / XR; p = atomicAdd(&cur[bb + g], 1);
    stage[p] = (unsigned)sv.x | ((unsigned)(d.x - g * XR) << 17);
    g = d.y / XR; p = atomicAdd(&cur[bb + g], 1);
    stage[p] = (unsigned)sv.y | ((unsigned)(d.y - g * XR) << 17);
    g = d.z / XR; p = atomicAdd(&cur[bb + g], 1);
    stage[p] = (unsigned)sv.z | ((unsigned)(d.z - g * XR) << 17);
    g = d.w / XR; p = atomicAdd(&cur[bb + g], 1);
    stage[p] = (unsigned)sv.w | ((unsigned)(d.w - g * XR) << 17);
  }
}

// Fill padded CSR for one direction. Group g reads ONLY its ~1.6 MB bucket and
// scatters into its 2.4 MB csr slice -> slice stays L2-resident, lines written
// back once. deg atomics are XCD-local.
__global__ __launch_bounds__(256) void k_fillb(const unsigned* __restrict__ stage,
                                               const int* __restrict__ base,
                                               int* __restrict__ deg,
                                               int* __restrict__ csr,
                                               int dirbase){
  const int g = blockIdx.x & 7;
  const int j = blockIdx.x >> 3, NJ = gridDim.x >> 3;
  const int bb = dirbase + g;
  const int beg = base[bb * HB];
  const int end = base[(bb + 1) * HB];
  for (int i = beg + j * 256 + threadIdx.x; i < end; i += NJ * 256){
    unsigned p = __builtin_nontemporal_load(stage + i);
    int node = g * XR + (int)(p >> 17);
    int pos = atomicAdd(&deg[node], 1);
    if (pos < PS) csr[node * PS + pos] = (int)(p & 0x1FFFFu);
  }
}

// ===================== fp32 -> bf16 convert (both inputs) ====================
__global__ __launch_bounds__(256) void k_cvt2(const float* __restrict__ ina,
                                              const float* __restrict__ inb,
                                              u16* __restrict__ oa,
                                              u16* __restrict__ ob, int n8){
  int i = blockIdx.x * 256 + threadIdx.x;
  const float* in = ina; u16* out = oa;
  if (i >= n8){ i -= n8; in = inb; out = ob; }
  floatx4 a = __builtin_nontemporal_load((const floatx4*)in + (size_t)i * 2);
  floatx4 b = __builtin_nontemporal_load((const floatx4*)in + (size_t)i * 2 + 1);
  u16 v[8] = { f2bf(a[0]), f2bf(a[1]), f2bf(a[2]), f2bf(a[3]),
               f2bf(b[0]), f2bf(b[1]), f2bf(b[2]), f2bf(b[3]) };
  *(uint4*)(out + (size_t)i * 8) = *(const uint4*)v;
}

// ===================== weight pre-swizzle (all weights, one kernel) ==========
__global__ __launch_bounds__(256) void k_prep(const float* __restrict__ Wl_tgt,
    const float* __restrict__ Wr_tgt, const float* __restrict__ Wl_src,
    const float* __restrict__ Wr_src, const float* __restrict__ Wo,
    u16* __restrict__ Wsw0, u16* __restrict__ Wsw1, u16* __restrict__ Wsw2,
    u16* __restrict__ Wswo){
  int b = blockIdx.x;
  if (b < 48){
    const float *Wl, *Wr; u16* dst;
    if (b < 16){ Wl = Wl_tgt; Wr = Wr_tgt; dst = Wsw0; }
    else if (b < 32){ Wl = Wl_src; Wr = Wr_src; dst = Wsw1; b -= 16; }
    else { Wl = Wl_src + 16384; Wr = Wr_src + 16384; dst = Wsw2; b -= 32; }
    int idx = b * 256 + threadIdx.x;        // 0..4095
    int lane = idx & 63, tile = idx >> 6;   // tile = kt*8+nt
    int kt = tile >> 3, nt = tile & 7;
    int n = nt * 16 + (lane & 15);
    int kb = kt * 32 + (lane >> 4) * 8;
    u16 v[8];
    #pragma unroll
    for (int j = 0; j < 8; ++j){
      int k = kb + j;
      float w = (k < 128) ? Wl[(size_t)k * 128 + n] : Wr[(size_t)(k - 128) * 128 + n];
      v[j] = f2bf(w);
    }
    *(uint4*)(dst + (size_t)idx * 8) = *(const uint4*)v;
  } else {
    int idx = (b - 48) * 256 + threadIdx.x; // 0..1023
    int lane = idx & 63, tile = idx >> 6;   // tile = kt*4+nt
    int kt = tile >> 2, nt = tile & 3;
    int n = nt * 16 + (lane & 15);
    int kb = kt * 32 + (lane >> 4) * 8;
    u16 v[8];
    #pragma unroll
    for (int j = 0; j < 8; ++j)
      v[j] = f2bf(Wo[(size_t)(kb + j) * 64 + n]);
    *(uint4*)(Wswo + (size_t)idx * 8) = *(const uint4*)v;
  }
}

// ===================== mean aggregation ======================================
// 1 wave/row; 4 lane-groups of 16: each gather instruction reads one FULL
// 256 B feature row (16 lanes x 16 B) -> 4 edges per instruction, unroll x2
// for 8 outstanding. Reduce across groups with shfl_xor(16,32).
__global__ __launch_bounds__(256) void k_agg(const u16* __restrict__ x,
                                             const int* __restrict__ deg,
                                             const int* __restrict__ csr,
                                             u16* __restrict__ out){
  const int row  = blockIdx.x * 4 + (threadIdx.x >> 6);
  const int lane = threadIdx.x & 63;
  const int sub = lane >> 4, l4 = lane & 15;
  int cnt = deg[row];
  if (cnt > PS) cnt = PS;
  const int beg = row * PS;
  float a[8] = {0.f,0.f,0.f,0.f,0.f,0.f,0.f,0.f};
  int e = 0;
  for (; e + 7 < cnt; e += 8){
    int s0 = csr[beg + e + sub];
    int s1 = csr[beg + e + 4 + sub];
    uint4 v0 = *(const uint4*)(x + (size_t)s0 * DD + l4 * 8);
    uint4 v1 = *(const uint4*)(x + (size_t)s1 * DD + l4 * 8);
    a[0] += __uint_as_float(v0.x << 16); a[1] += __uint_as_float(v0.x & 0xFFFF0000u);
    a[2] += __uint_as_float(v0.y << 16); a[3] += __uint_as_float(v0.y & 0xFFFF0000u);
    a[4] += __uint_as_float(v0.z << 16); a[5] += __uint_as_float(v0.z & 0xFFFF0000u);
    a[6] += __uint_as_float(v0.w << 16); a[7] += __uint_as_float(v0.w & 0xFFFF0000u);
    a[0] += __uint_as_float(v1.x << 16); a[1] += __uint_as_float(v1.x & 0xFFFF0000u);
    a[2] += __uint_as_float(v1.y << 16); a[3] += __uint_as_float(v1.y & 0xFFFF0000u);
    a[4] += __uint_as_float(v1.z << 16); a[5] += __uint_as_float(v1.z & 0xFFFF0000u);
    a[6] += __uint_as_float(v1.w << 16); a[7] += __uint_as_float(v1.w & 0xFFFF0000u);
  }
  for (; e + 3 < cnt; e += 4){
    int s0 = csr[beg + e + sub];
    uint4 v0 = *(const uint4*)(x + (size_t)s0 * DD + l4 * 8);
    a[0] += __uint_as_float(v0.x << 16); a[1] += __uint_as_float(v0.x & 0xFFFF0000u);
    a[2] += __uint_as_float(v0.y << 16); a[3] += __uint_as_float(v0.y & 0xFFFF0000u);
    a[4] += __uint_as_float(v0.z << 16); a[5] += __uint_as_float(v0.z & 0xFFFF0000u);
    a[6] += __uint_as_float(v0.w << 16); a[7] += __uint_as_float(v0.w & 0xFFFF0000u);
  }
  if (e + sub < cnt){
    int s0 = csr[beg + e + sub];
    uint4 v0 = *(const uint4*)(x + (size_t)s0 * DD + l4 * 8);
    a[0] += __uint_as_float(v0.x << 16); a[1] += __uint_as_float(v0.x & 0xFFFF0000u);
    a[2] += __uint_as_float(v0.y << 16); a[3] += __uint_as_float(v0.y & 0xFFFF0000u);
    a[4] += __uint_as_float(v0.z << 16); a[5] += __uint_as_float(v0.z & 0xFFFF0000u);
    a[6] += __uint_as_float(v0.w << 16); a[7] += __uint_as_float(v0.w & 0xFFFF0000u);
  }
  #pragma unroll
  for (int i = 0; i < 8; ++i){
    a[i] += __shfl_xor(a[i], 16);
    a[i] += __shfl_xor(a[i], 32);
  }
  const float inv = (cnt > 0) ? (1.0f / (float)cnt) : 1.0f;
  if (sub == 0){
    unsigned pk[4];
    #pragma unroll
    for (int i = 0; i < 4; ++i)
      pk[i] = (unsigned)f2bf(a[2*i] * inv) | ((unsigned)f2bf(a[2*i+1] * inv) << 16);
    *(uint4*)(out + (size_t)row * DD + l4 * 8) = make_uint4(pk[0], pk[1], pk[2], pk[3]);
  }
}

// ===================== fused layer GEMM via MFMA =============================
__global__ __launch_bounds__(256) void k_fused(const u16* __restrict__ Am,
    const u16* __restrict__ X, const u16* __restrict__ Wsw,
    const float* __restrict__ bias, u16* __restrict__ outH,
    unsigned key0, unsigned key1)
{
  const int wave = threadIdx.x >> 6, lane = threadIdx.x & 63;
  const int quad = lane >> 4, col0 = lane & 15;
  const int row0 = blockIdx.x * 64 + wave * 16;
  int m = row0 + col0;
  if (m >= NN) m = NN - 1;

  floatx4 acc[8];
  #pragma unroll
  for (int i = 0; i < 8; ++i) acc[i] = (floatx4)0.f;

  #pragma unroll
  for (int kt = 0; kt < 8; ++kt){
    const int k = kt * 32 + quad * 8;
    const u16* ap = (k < 128) ? (Am + (size_t)m * 128 + k)
                              : (X  + (size_t)m * 128 + (k - 128));
    short8 a = __builtin_nontemporal_load((const short8*)ap);
    #pragma unroll
    for (int nt = 0; nt < 8; ++nt){
      short8 b = *(const short8*)(Wsw + (size_t)(((kt * 8 + nt) * 64 + lane) * 8));
      acc[nt] = __builtin_amdgcn_mfma_f32_16x16x32_bf16(a, b, acc[nt], 0, 0, 0);
    }
  }

  #pragma unroll
  for (int nt = 0; nt < 8; ++nt){
    const int col = nt * 16 + col0;
    const float bj = bias[col];
    #pragma unroll
    for (int rg = 0; rg < 4; ++rg){
      const int r = row0 + quad * 4 + rg;
      if (r < NN){
        float h = acc[nt][rg] + bj;
        h = (h >= 0.f) ? h : 0.01f * h;
        unsigned j = (unsigned)r * 128u + (unsigned)col;
        h *= drop_scale(key0, key1, j);
        outH[(size_t)r * 128 + col] = f2bf(h);
      }
    }
  }
}

// ===================== output GEMM via MFMA (fp32 out) =======================
__global__ __launch_bounds__(256) void k_out(const u16* __restrict__ H,
    const u16* __restrict__ Wsw, const float* __restrict__ bias,
    float* __restrict__ out)
{
  const int wave = threadIdx.x >> 6, lane = threadIdx.x & 63;
  const int quad = lane >> 4, col0 = lane & 15;
  const int row0 = blockIdx.x * 64 + wave * 16;
  int m = row0 + col0;
  if (m >= NN) m = NN - 1;

  floatx4 acc[4];
  #pragma unroll
  for (int i = 0; i < 4; ++i) acc[i] = (floatx4)0.f;

  #pragma unroll
  for (int kt = 0; kt < 4; ++kt){
    short8 a = __builtin_nontemporal_load(
        (const short8*)(H + (size_t)m * 128 + kt * 32 + quad * 8));
    #pragma unroll
    for (int nt = 0; nt < 4; ++nt){
      short8 b = *(const short8*)(Wsw + (size_t)(((kt * 4 + nt) * 64 + lane) * 8));
      acc[nt] = __builtin_amdgcn_mfma_f32_16x16x32_bf16(a, b, acc[nt], 0, 0, 0);
    }
  }

  #pragma unroll
  for (int nt = 0; nt < 4; ++nt){
    const int col = nt * 16 + col0;
    const float bj = bias[col];
    #pragma unroll
    for (int rg = 0; rg < 4; ++rg){
      const int r = row0 + quad * 4 + rg;
      if (r < NN)
        out[(size_t)r * 64 + col] = acc[nt][rg] + bj;
    }
  }
}

// ===================== launch =====================
extern "C" void kernel_launch(void* const* d_in, const int* in_sizes, int n_in,
                              void* d_out, int out_size, void* d_ws, size_t ws_size,
                              hipStream_t stream)
{
  const float* x_src  = (const float*)d_in[0];
  const float* x_tgt  = (const float*)d_in[1];
  const float* Wl_tgt = (const float*)d_in[2];
  const float* bl_tgt = (const float*)d_in[3];
  const float* Wr_tgt = (const float*)d_in[4];
  const float* Wl_src = (const float*)d_in[5];
  const float* bl_src = (const float*)d_in[6];
  const float* Wr_src = (const float*)d_in[7];
  const float* W_o    = (const float*)d_in[8];
  const float* b_o    = (const float*)d_in[9];
  const int*   e_src  = (const int*)d_in[10];
  const int*   e_dst  = (const int*)d_in[11];
  const int*   r_src  = (const int*)d_in[12];
  const int*   r_dst  = (const int*)d_in[13];
  float* out = (float*)d_out;
  (void)in_sizes; (void)n_in; (void)out_size; (void)ws_size;

  char* ws = (char*)d_ws;
  size_t off = 0;
  auto alloc = [&](size_t bytes) -> char* {
    char* p = ws + off; off += (bytes + 255) & ~(size_t)255; return p;
  };
  u16* Xs    = (u16*)alloc((size_t)NN * DD * 2);   // bf16 x_source
  u16* Xt    = (u16*)alloc((size_t)NN * DD * 2);   // bf16 x_target
  u16* A     = (u16*)alloc((size_t)NN * DD * 2);   // agg scratch (bf16)
  u16* B     = (u16*)alloc((size_t)NN * DD * 2);   // h_t(l0), then h_s(l1)
  u16* C     = (u16*)alloc((size_t)NN * DD * 2);   // h_s(l0)
  u16* Wsw0  = (u16*)alloc(256 * 128 * 2);
  u16* Wsw1  = (u16*)alloc(256 * 128 * 2);
  u16* Wsw2  = (u16*)alloc(256 * 128 * 2);
  u16* Wswo  = (u16*)alloc(128 * 64 * 2);
  int* deg   = (int*)alloc((size_t)2 * NN * 4);    // deg_t | deg_s
  int* deg_t = deg;
  int* deg_s = deg + NN;
  int* csr_e = (int*)alloc((size_t)NN * PS * 4);   // padded CSR (19.2 MB)
  int* csr_r = (int*)alloc((size_t)NN * PS * 4);
  int* hist  = (int*)alloc((size_t)(16 * HB + 1) * 4);
  unsigned* stage = (unsigned*)alloc((size_t)2 * NE * 4);  // 12.8 MB

  // dropout keys: fold_in(key(42), d) = threefry([0,42],[0,d]); d in {0,1,3}
  unsigned kt0a, kt0b, ks0a, ks0b, ks1a, ks1b;
  tf2x32(0u, 42u, 0u, 0u, kt0a, kt0b);   // layer0 new_t
  tf2x32(0u, 42u, 0u, 1u, ks0a, ks0b);   // layer0 new_s
  tf2x32(0u, 42u, 0u, 3u, ks1a, ks1b);   // layer1 new_s

  hipMemsetAsync(deg, 0, (size_t)2 * NN * 4, stream);

  const int CB = NN * DD / 8 / 256;          // 6250

  // prep work
  k_cvt2<<<2 * CB, 256, 0, stream>>>(x_src, x_tgt, Xs, Xt, NN * DD / 8);
  k_prep<<<52, 256, 0, stream>>>(Wl_tgt, Wr_tgt, Wl_src, Wr_src, W_o,
                                 Wsw0, Wsw1, Wsw2, Wswo);

  // edge partition + padded CSR build
  k_hist<<<HB, 256, 0, stream>>>(e_dst, r_dst, hist);
  k_scan<<<1, 256, 0, stream>>>(hist);
  k_scatter<<<HB, 256, 0, stream>>>(e_src, e_dst, r_src, r_dst, hist, stage);
  k_fillb<<<8 * 32, 256, 0, stream>>>(stage, hist, deg_t, csr_e, 0);
  k_fillb<<<8 * 32, 256, 0, stream>>>(stage, hist, deg_s, csr_r, 8);

  const int GB = (NN + 63) / 64;    // 1563
  const int AB = NN / 4;            // 25000
  // layer 0, target side: new_t = f(mean(x_src), x_tgt)
  k_agg<<<AB, 256, 0, stream>>>(Xs, deg_t, csr_e, A);
  k_fused<<<GB, 256, 0, stream>>>(A, Xt, Wsw0, bl_tgt, B, kt0a, kt0b);
  // layer 0, source side: new_s = f(mean(x_tgt), x_src)
  k_agg<<<AB, 256, 0, stream>>>(Xt, deg_s, csr_r, A);
  k_fused<<<GB, 256, 0, stream>>>(A, Xs, Wsw1, bl_src, C, ks0a, ks0b);
  // layer 1, source side only (layer-1 target output is dead)
  k_agg<<<AB, 256, 0, stream>>>(B, deg_s, csr_r, A);
  k_fused<<<GB, 256, 0, stream>>>(A, C, Wsw2, bl_src + 128, B, ks1a, ks1b);
  // out = h_s1 @ W_out + b_out
  k_out<<<GB, 256, 0, stream>>>(B, Wswo, b_o, out);
}

// Round 8
// 589.931 us; speedup vs baseline: 2.2442x; 1.1138x over previous
//
#include <hip/hip_runtime.h>
#include <stdint.h>

#define NN 100000     // N_SRC == N_TGT
#define NE 1600000
#define DD 128
#define PS 48         // padded CSR slots per node (deg: mean 16, max ~45)
#define HB 1024       // hist/scatter1 grid
#define G8 12544      // nodes per top bucket = 128 * 98
#define SUBN 98       // nodes per sub-bucket
#define NSUB 128      // sub-buckets per top bucket
#define NND 100352    // padded node count = 1024 * 98
#define K2 16         // chunks per top bucket (hist2/scatter2)
#define RCAP 2304     // record cap per sub-bucket (mean 1568, sd ~40)

typedef unsigned short u16;
typedef short short8 __attribute__((ext_vector_type(8)));
typedef float floatx4 __attribute__((ext_vector_type(4)));
typedef int intx4 __attribute__((ext_vector_type(4)));

// ===================== helpers =====================
__device__ static inline u16 f2bf(float f){
  unsigned u = __float_as_uint(f);
  unsigned r = u + 0x7FFFu + ((u >> 16) & 1u);   // RNE
  return (u16)(r >> 16);
}

// ===================== threefry2x32 (JAX-compatible) =====================
__host__ __device__ static inline unsigned rotl32(unsigned x, int r){
  return (x << r) | (x >> (32 - r));
}

__host__ __device__ static inline void tf2x32(unsigned k0, unsigned k1,
                                              unsigned c0, unsigned c1,
                                              unsigned &o0, unsigned &o1)
{
  const unsigned ks2 = k0 ^ k1 ^ 0x1BD11BDAu;
  unsigned x0 = c0 + k0, x1 = c1 + k1;
#define TFR(r) { x0 += x1; x1 = rotl32(x1, (r)); x1 ^= x0; }
  TFR(13) TFR(15) TFR(26) TFR(6)   x0 += k1;  x1 += ks2 + 1u;
  TFR(17) TFR(29) TFR(16) TFR(24)  x0 += ks2; x1 += k0 + 2u;
  TFR(13) TFR(15) TFR(26) TFR(6)   x0 += k0;  x1 += k1 + 3u;
  TFR(17) TFR(29) TFR(16) TFR(24)  x0 += k1;  x1 += ks2 + 4u;
  TFR(13) TFR(15) TFR(26) TFR(6)   x0 += ks2; x1 += k0 + 5u;
#undef TFR
  o0 = x0; o1 = x1;
}

__device__ static inline float drop_scale(unsigned k0, unsigned k1, unsigned j)
{
  unsigned o0, o1;
  tf2x32(k0, k1, 0u, j, o0, o1);
  const unsigned bits = o0 ^ o1;
  const float u = __uint_as_float((bits >> 9) | 0x3F800000u) - 1.0f;
  return (u < 0.9f) ? (1.0f / 0.9f) : 0.0f;
}

// ===================== level-1 partition: 16 buckets (dir x 8 ranges) ========
__global__ __launch_bounds__(256) void k_hist(const int* __restrict__ e_dst,
                                              const int* __restrict__ r_dst,
                                              int* __restrict__ hist){
  __shared__ int h[16];
  const int t = threadIdx.x;
  if (t < 16) h[t] = 0;
  __syncthreads();
  const int QT = 2 * (NE / 4);
  for (int i = blockIdx.x * 256 + t; i < QT; i += HB * 256){
    int dir = (i >= NE / 4);
    int qi = dir ? i - NE / 4 : i;
    const int* dp = dir ? r_dst : e_dst;
    intx4 d = __builtin_nontemporal_load((const intx4*)dp + qi);
    int bb = dir << 3;
    atomicAdd(&h[bb + d.x / G8], 1);
    atomicAdd(&h[bb + d.y / G8], 1);
    atomicAdd(&h[bb + d.z / G8], 1);
    atomicAdd(&h[bb + d.w / G8], 1);
  }
  __syncthreads();
  if (t < 16) hist[t * HB + blockIdx.x] = h[t];
}

// Exclusive scan over hist[16*HB] (bucket-major); hist[16*HB] = total.
// Comb order within a bucket is a permutation -> still valid disjoint ranges,
// and element (bucket, blk=0) (owned by the first comb thread) holds the
// bucket's true start.
__global__ __launch_bounds__(256) void k_scanA(int* __restrict__ hist){
  __shared__ int sh[16 * HB];
  __shared__ int tot[256];
  const int t = threadIdx.x;
  const int N = 16 * HB;
  for (int k = t; k < N; k += 256) sh[k] = hist[k];
  __syncthreads();
  int s = 0;
  #pragma unroll 4
  for (int k = 0; k < 64; ++k)
    s += sh[(t >> 4) * HB + (t & 15) + (k << 4)];
  tot[t] = s;
  __syncthreads();
  int v = s;
  for (int off = 1; off < 256; off <<= 1){
    int u = (t >= off) ? tot[t - off] : 0;
    __syncthreads();
    tot[t] += u;
    __syncthreads();
  }
  int run = tot[t] - v;
  for (int k = 0; k < 64; ++k){
    int idx = (t >> 4) * HB + (t & 15) + (k << 4);
    int xv = sh[idx];
    sh[idx] = run;
    run += xv;
  }
  __syncthreads();
  for (int k = t; k < N; k += 256) hist[k] = sh[k];
  if (t == 255) hist[N] = tot[255];   // grand total = 2*NE
}

// Scatter into 16 bucket-contiguous regions. Record = (node_local<<17)|src,
// node_local = dst - g*G8 (<12544, 14 bits), src < 2^17.
__global__ __launch_bounds__(256) void k_scatter1(const int* __restrict__ e_src,
                                                  const int* __restrict__ e_dst,
                                                  const int* __restrict__ r_src,
                                                  const int* __restrict__ r_dst,
                                                  const int* __restrict__ base,
                                                  unsigned* __restrict__ stage){
  __shared__ int cur[16];
  const int t = threadIdx.x;
  if (t < 16) cur[t] = base[t * HB + blockIdx.x];
  __syncthreads();
  const int QT = 2 * (NE / 4);
  for (int i = blockIdx.x * 256 + t; i < QT; i += HB * 256){
    int dir = (i >= NE / 4);
    int qi = dir ? i - NE / 4 : i;
    const int* dp = dir ? r_dst : e_dst;
    const int* sp = dir ? r_src : e_src;
    intx4 d = __builtin_nontemporal_load((const intx4*)dp + qi);
    intx4 sv = __builtin_nontemporal_load((const intx4*)sp + qi);
    int bb = dir << 3;
    int g, p;
    g = d.x / G8; p = atomicAdd(&cur[bb + g], 1);
    stage[p] = (unsigned)sv.x | ((unsigned)(d.x - g * G8) << 17);
    g = d.y / G8; p = atomicAdd(&cur[bb + g], 1);
    stage[p] = (unsigned)sv.y | ((unsigned)(d.y - g * G8) << 17);
    g = d.z / G8; p = atomicAdd(&cur[bb + g], 1);
    stage[p] = (unsigned)sv.z | ((unsigned)(d.z - g * G8) << 17);
    g = d.w / G8; p = atomicAdd(&cur[bb + g], 1);
    stage[p] = (unsigned)sv.w | ((unsigned)(d.w - g * G8) << 17);
  }
}

// ===================== level-2 partition: 128 sub-buckets per bucket =========
// Grid 256 = (b16, k). Block (b16,k) combs its bucket with stride K2*256;
// hist2[(b16*NSUB+s)*K2 + k] = count.
__global__ __launch_bounds__(256) void k_hist2(const unsigned* __restrict__ stage,
                                               const int* __restrict__ base,
                                               int* __restrict__ hist2){
  __shared__ int h2[NSUB];
  const int b16 = blockIdx.x / K2, k = blockIdx.x % K2;
  const int t = threadIdx.x;
  if (t < NSUB) h2[t] = 0;
  __syncthreads();
  const int beg = base[b16 * HB];
  const int end = base[(b16 + 1) * HB];
  for (int i = beg + k * 256 + t; i < end; i += K2 * 256){
    unsigned p = stage[i];
    atomicAdd(&h2[(int)(p >> 17) / SUBN], 1);
  }
  __syncthreads();
  if (t < NSUB) hist2[(b16 * NSUB + t) * K2 + k] = h2[t];
}

// Ordered exclusive scan over hist2[32768] (one block; thread t owns a
// contiguous run of 128 elements).
__global__ __launch_bounds__(256) void k_scanB(int* __restrict__ hist2){
  __shared__ int sh[16 * NSUB * K2];   // 32768 ints = 128 KB
  __shared__ int tot[256];
  const int t = threadIdx.x;
  const int N = 16 * NSUB * K2;
  for (int k = t; k < N; k += 256) sh[k] = hist2[k];
  __syncthreads();
  int s = 0;
  for (int j = 0; j < 128; ++j) s += sh[t * 128 + j];
  tot[t] = s;
  __syncthreads();
  int v = s;
  for (int off = 1; off < 256; off <<= 1){
    int u = (t >= off) ? tot[t - off] : 0;
    __syncthreads();
    tot[t] += u;
    __syncthreads();
  }
  int run = tot[t] - v;
  for (int j = 0; j < 128; ++j){
    int xv = sh[t * 128 + j];
    sh[t * 128 + j] = run;
    run += xv;
  }
  __syncthreads();
  for (int k = t; k < N; k += 256) hist2[k] = sh[k];
}

// Scatter bucket -> sub-bucket-contiguous stage2. Same comb mapping as hist2.
__global__ __launch_bounds__(256) void k_scatter2(const unsigned* __restrict__ stage,
                                                  const int* __restrict__ base,
                                                  const int* __restrict__ h2s,
                                                  unsigned* __restrict__ stage2){
  __shared__ int cur[NSUB];
  const int b16 = blockIdx.x / K2, k = blockIdx.x % K2;
  const int t = threadIdx.x;
  if (t < NSUB) cur[t] = h2s[(b16 * NSUB + t) * K2 + k];
  __syncthreads();
  const int beg = base[b16 * HB];
  const int end = base[(b16 + 1) * HB];
  for (int i = beg + k * 256 + t; i < end; i += K2 * 256){
    unsigned p = stage[i];
    int pos = atomicAdd(&cur[(int)(p >> 17) / SUBN], 1);
    stage2[pos] = p;
  }
}

// ===================== LDS counting-sort fill ================================
// One block per sub-bucket (2048 total, both dirs). Sort the ~1.6K records in
// LDS, then write the 98-row padded csr region as DENSE uint4 stores (every
// line written exactly once, within one block's lifetime) + coalesced deg.
__global__ __launch_bounds__(256) void k_fill3(const unsigned* __restrict__ stage2,
                                               const int* __restrict__ h2s,
                                               int* __restrict__ deg,
                                               int* __restrict__ csr){
  __shared__ unsigned rec[RCAP];
  __shared__ unsigned srt[RCAP];
  __shared__ int ldeg[SUBN], lptr[SUBN], lcur[SUBN];
  const int sb = blockIdx.x;              // 0..2047
  const int b16 = sb >> 7, sub = sb & 127;
  const int dir = b16 >> 3, g = b16 & 7;
  const int t = threadIdx.x;
  const int beg = h2s[sb * K2];
  const int end = (sb == 2047) ? 2 * NE : h2s[(sb + 1) * K2];
  int n = end - beg;
  if (n > RCAP) n = RCAP;
  for (int i = t; i < n; i += 256) rec[i] = stage2[beg + i];
  if (t < SUBN) ldeg[t] = 0;
  __syncthreads();
  const int nl0 = sub * SUBN;
  for (int i = t; i < n; i += 256)
    atomicAdd(&ldeg[(int)(rec[i] >> 17) - nl0], 1);
  __syncthreads();
  if (t == 0){
    int run = 0;
    for (int s = 0; s < SUBN; ++s){ lptr[s] = run; lcur[s] = run; run += ldeg[s]; }
  }
  __syncthreads();
  for (int i = t; i < n; i += 256){
    int rl = (int)(rec[i] >> 17) - nl0;
    int pos = atomicAdd(&lcur[rl], 1);
    srt[pos] = rec[i] & 0x1FFFFu;
  }
  __syncthreads();
  const int node0 = g * G8 + nl0;
  int* degd = deg + dir * NND;
  int* csrd = csr + (size_t)dir * NND * PS;
  if (t < SUBN) degd[node0 + t] = ldeg[t];
  const int base4 = node0 * (PS / 4);
  for (int j4 = t; j4 < SUBN * (PS / 4); j4 += 256){   // 1176 uint4s, dense
    int row = j4 / (PS / 4);
    int s4 = (j4 % (PS / 4)) * 4;
    int d0 = ldeg[row], p0 = lptr[row];
    uint4 v;
    v.x = (s4 + 0 < d0) ? srt[p0 + s4 + 0] : 0u;
    v.y = (s4 + 1 < d0) ? srt[p0 + s4 + 1] : 0u;
    v.z = (s4 + 2 < d0) ? srt[p0 + s4 + 2] : 0u;
    v.w = (s4 + 3 < d0) ? srt[p0 + s4 + 3] : 0u;
    ((uint4*)csrd)[base4 + j4] = v;
  }
}

// ===================== fp32 -> bf16 convert (both inputs) ====================
__global__ __launch_bounds__(256) void k_cvt2(const float* __restrict__ ina,
                                              const float* __restrict__ inb,
                                              u16* __restrict__ oa,
                                              u16* __restrict__ ob, int n8){
  int i = blockIdx.x * 256 + threadIdx.x;
  const float* in = ina; u16* out = oa;
  if (i >= n8){ i -= n8; in = inb; out = ob; }
  floatx4 a = __builtin_nontemporal_load((const floatx4*)in + (size_t)i * 2);
  floatx4 b = __builtin_nontemporal_load((const floatx4*)in + (size_t)i * 2 + 1);
  u16 v[8] = { f2bf(a[0]), f2bf(a[1]), f2bf(a[2]), f2bf(a[3]),
               f2bf(b[0]), f2bf(b[1]), f2bf(b[2]), f2bf(b[3]) };
  *(uint4*)(out + (size_t)i * 8) = *(const uint4*)v;
}

// ===================== weight pre-swizzle (all weights, one kernel) ==========
__global__ __launch_bounds__(256) void k_prep(const float* __restrict__ Wl_tgt,
    const float* __restrict__ Wr_tgt, const float* __restrict__ Wl_src,
    const float* __restrict__ Wr_src, const float* __restrict__ Wo,
    u16* __restrict__ Wsw0, u16* __restrict__ Wsw1, u16* __restrict__ Wsw2,
    u16* __restrict__ Wswo){
  int b = blockIdx.x;
  if (b < 48){
    const float *Wl, *Wr; u16* dst;
    if (b < 16){ Wl = Wl_tgt; Wr = Wr_tgt; dst = Wsw0; }
    else if (b < 32){ Wl = Wl_src; Wr = Wr_src; dst = Wsw1; b -= 16; }
    else { Wl = Wl_src + 16384; Wr = Wr_src + 16384; dst = Wsw2; b -= 32; }
    int idx = b * 256 + threadIdx.x;
    int lane = idx & 63, tile = idx >> 6;
    int kt = tile >> 3, nt = tile & 7;
    int n = nt * 16 + (lane & 15);
    int kb = kt * 32 + (lane >> 4) * 8;
    u16 v[8];
    #pragma unroll
    for (int j = 0; j < 8; ++j){
      int k = kb + j;
      float w = (k < 128) ? Wl[(size_t)k * 128 + n] : Wr[(size_t)(k - 128) * 128 + n];
      v[j] = f2bf(w);
    }
    *(uint4*)(dst + (size_t)idx * 8) = *(const uint4*)v;
  } else {
    int idx = (b - 48) * 256 + threadIdx.x;
    int lane = idx & 63, tile = idx >> 6;
    int kt = tile >> 2, nt = tile & 3;
    int n = nt * 16 + (lane & 15);
    int kb = kt * 32 + (lane >> 4) * 8;
    u16 v[8];
    #pragma unroll
    for (int j = 0; j < 8; ++j)
      v[j] = f2bf(Wo[(size_t)(kb + j) * 64 + n]);
    *(uint4*)(Wswo + (size_t)idx * 8) = *(const uint4*)v;
  }
}

// ===================== mean aggregation ======================================
__global__ __launch_bounds__(256) void k_agg(const u16* __restrict__ x,
                                             const int* __restrict__ deg,
                                             const int* __restrict__ csr,
                                             u16* __restrict__ out){
  const int row  = blockIdx.x * 4 + (threadIdx.x >> 6);
  const int lane = threadIdx.x & 63;
  const int sub = lane >> 4, l4 = lane & 15;
  int cnt = deg[row];
  if (cnt > PS) cnt = PS;
  const int beg = row * PS;
  float a[8] = {0.f,0.f,0.f,0.f,0.f,0.f,0.f,0.f};
  int e = 0;
  for (; e + 7 < cnt; e += 8){
    int s0 = csr[beg + e + sub];
    int s1 = csr[beg + e + 4 + sub];
    uint4 v0 = *(const uint4*)(x + (size_t)s0 * DD + l4 * 8);
    uint4 v1 = *(const uint4*)(x + (size_t)s1 * DD + l4 * 8);
    a[0] += __uint_as_float(v0.x << 16); a[1] += __uint_as_float(v0.x & 0xFFFF0000u);
    a[2] += __uint_as_float(v0.y << 16); a[3] += __uint_as_float(v0.y & 0xFFFF0000u);
    a[4] += __uint_as_float(v0.z << 16); a[5] += __uint_as_float(v0.z & 0xFFFF0000u);
    a[6] += __uint_as_float(v0.w << 16); a[7] += __uint_as_float(v0.w & 0xFFFF0000u);
    a[0] += __uint_as_float(v1.x << 16); a[1] += __uint_as_float(v1.x & 0xFFFF0000u);
    a[2] += __uint_as_float(v1.y << 16); a[3] += __uint_as_float(v1.y & 0xFFFF0000u);
    a[4] += __uint_as_float(v1.z << 16); a[5] += __uint_as_float(v1.z & 0xFFFF0000u);
    a[6] += __uint_as_float(v1.w << 16); a[7] += __uint_as_float(v1.w & 0xFFFF0000u);
  }
  for (; e + 3 < cnt; e += 4){
    int s0 = csr[beg + e + sub];
    uint4 v0 = *(const uint4*)(x + (size_t)s0 * DD + l4 * 8);
    a[0] += __uint_as_float(v0.x << 16); a[1] += __uint_as_float(v0.x & 0xFFFF0000u);
    a[2] += __uint_as_float(v0.y << 16); a[3] += __uint_as_float(v0.y & 0xFFFF0000u);
    a[4] += __uint_as_float(v0.z << 16); a[5] += __uint_as_float(v0.z & 0xFFFF0000u);
    a[6] += __uint_as_float(v0.w << 16); a[7] += __uint_as_float(v0.w & 0xFFFF0000u);
  }
  if (e + sub < cnt){
    int s0 = csr[beg + e + sub];
    uint4 v0 = *(const uint4*)(x + (size_t)s0 * DD + l4 * 8);
    a[0] += __uint_as_float(v0.x << 16); a[1] += __uint_as_float(v0.x & 0xFFFF0000u);
    a[2] += __uint_as_float(v0.y << 16); a[3] += __uint_as_float(v0.y & 0xFFFF0000u);
    a[4] += __uint_as_float(v0.z << 16); a[5] += __uint_as_float(v0.z & 0xFFFF0000u);
    a[6] += __uint_as_float(v0.w << 16); a[7] += __uint_as_float(v0.w & 0xFFFF0000u);
  }
  #pragma unroll
  for (int i = 0; i < 8; ++i){
    a[i] += __shfl_xor(a[i], 16);
    a[i] += __shfl_xor(a[i], 32);
  }
  const float inv = (cnt > 0) ? (1.0f / (float)cnt) : 1.0f;
  if (sub == 0){
    unsigned pk[4];
    #pragma unroll
    for (int i = 0; i < 4; ++i)
      pk[i] = (unsigned)f2bf(a[2*i] * inv) | ((unsigned)f2bf(a[2*i+1] * inv) << 16);
    *(uint4*)(out + (size_t)row * DD + l4 * 8) = make_uint4(pk[0], pk[1], pk[2], pk[3]);
  }
}

// ===================== fused layer GEMM via MFMA =============================
__global__ __launch_bounds__(256) void k_fused(const u16* __restrict__ Am,
    const u16* __restrict__ X, const u16* __restrict__ Wsw,
    const float* __restrict__ bias, u16* __restrict__ outH,
    unsigned key0, unsigned key1)
{
  const int wave = threadIdx.x >> 6, lane = threadIdx.x & 63;
  const int quad = lane >> 4, col0 = lane & 15;
  const int row0 = blockIdx.x * 64 + wave * 16;
  int m = row0 + col0;
  if (m >= NN) m = NN - 1;

  floatx4 acc[8];
  #pragma unroll
  for (int i = 0; i < 8; ++i) acc[i] = (floatx4)0.f;

  #pragma unroll
  for (int kt = 0; kt < 8; ++kt){
    const int k = kt * 32 + quad * 8;
    const u16* ap = (k < 128) ? (Am + (size_t)m * 128 + k)
                              : (X  + (size_t)m * 128 + (k - 128));
    short8 a = __builtin_nontemporal_load((const short8*)ap);
    #pragma unroll
    for (int nt = 0; nt < 8; ++nt){
      short8 b = *(const short8*)(Wsw + (size_t)(((kt * 8 + nt) * 64 + lane) * 8));
      acc[nt] = __builtin_amdgcn_mfma_f32_16x16x32_bf16(a, b, acc[nt], 0, 0, 0);
    }
  }

  #pragma unroll
  for (int nt = 0; nt < 8; ++nt){
    const int col = nt * 16 + col0;
    const float bj = bias[col];
    #pragma unroll
    for (int rg = 0; rg < 4; ++rg){
      const int r = row0 + quad * 4 + rg;
      if (r < NN){
        float h = acc[nt][rg] + bj;
        h = (h >= 0.f) ? h : 0.01f * h;
        unsigned j = (unsigned)r * 128u + (unsigned)col;
        h *= drop_scale(key0, key1, j);
        outH[(size_t)r * 128 + col] = f2bf(h);
      }
    }
  }
}

// ===================== output GEMM via MFMA (fp32 out) =======================
__global__ __launch_bounds__(256) void k_out(const u16* __restrict__ H,
    const u16* __restrict__ Wsw, const float* __restrict__ bias,
    float* __restrict__ out)
{
  const int wave = threadIdx.x >> 6, lane = threadIdx.x & 63;
  const int quad = lane >> 4, col0 = lane & 15;
  const int row0 = blockIdx.x * 64 + wave * 16;
  int m = row0 + col0;
  if (m >= NN) m = NN - 1;

  floatx4 acc[4];
  #pragma unroll
  for (int i = 0; i < 4; ++i) acc[i] = (floatx4)0.f;

  #pragma unroll
  for (int kt = 0; kt < 4; ++kt){
    short8 a = __builtin_nontemporal_load(
        (const short8*)(H + (size_t)m * 128 + kt * 32 + quad * 8));
    #pragma unroll
    for (int nt = 0; nt < 4; ++nt){
      short8 b = *(const short8*)(Wsw + (size_t)(((kt * 4 + nt) * 64 + lane) * 8));
      acc[nt] = __builtin_amdgcn_mfma_f32_16x16x32_bf16(a, b, acc[nt], 0, 0, 0);
    }
  }

  #pragma unroll
  for (int nt = 0; nt < 4; ++nt){
    const int col = nt * 16 + col0;
    const float bj = bias[col];
    #pragma unroll
    for (int rg = 0; rg < 4; ++rg){
      const int r = row0 + quad * 4 + rg;
      if (r < NN)
        out[(size_t)r * 64 + col] = acc[nt][rg] + bj;
    }
  }
}

// ===================== launch =====================
extern "C" void kernel_launch(void* const* d_in, const int* in_sizes, int n_in,
                              void* d_out, int out_size, void* d_ws, size_t ws_size,
                              hipStream_t stream)
{
  const float* x_src  = (const float*)d_in[0];
  const float* x_tgt  = (const float*)d_in[1];
  const float* Wl_tgt = (const float*)d_in[2];
  const float* bl_tgt = (const float*)d_in[3];
  const float* Wr_tgt = (const float*)d_in[4];
  const float* Wl_src = (const float*)d_in[5];
  const float* bl_src = (const float*)d_in[6];
  const float* Wr_src = (const float*)d_in[7];
  const float* W_o    = (const float*)d_in[8];
  const float* b_o    = (const float*)d_in[9];
  const int*   e_src  = (const int*)d_in[10];
  const int*   e_dst  = (const int*)d_in[11];
  const int*   r_src  = (const int*)d_in[12];
  const int*   r_dst  = (const int*)d_in[13];
  float* out = (float*)d_out;
  (void)in_sizes; (void)n_in; (void)out_size; (void)ws_size;

  char* ws = (char*)d_ws;
  size_t off = 0;
  auto alloc = [&](size_t bytes) -> char* {
    char* p = ws + off; off += (bytes + 255) & ~(size_t)255; return p;
  };
  // stage1+stage2 (25.6 MB) are dead after k_fill3; agg scratch A aliases them.
  unsigned* stage1 = (unsigned*)alloc((size_t)2 * NE * 4);
  unsigned* stage2 = (unsigned*)alloc((size_t)2 * NE * 4);
  u16* A     = (u16*)stage1;                       // [NN*DD] bf16, fits in 25.6MB
  u16* Xs    = (u16*)alloc((size_t)NN * DD * 2);
  u16* Xt    = (u16*)alloc((size_t)NN * DD * 2);
  u16* B     = (u16*)alloc((size_t)NN * DD * 2);   // h_t(l0), then h_s(l1)
  u16* C     = (u16*)alloc((size_t)NN * DD * 2);   // h_s(l0)
  u16* Wsw0  = (u16*)alloc(256 * 128 * 2);
  u16* Wsw1  = (u16*)alloc(256 * 128 * 2);
  u16* Wsw2  = (u16*)alloc(256 * 128 * 2);
  u16* Wswo  = (u16*)alloc(128 * 64 * 2);
  int* deg   = (int*)alloc((size_t)2 * NND * 4);   // dir-0 | dir-1
  int* csr   = (int*)alloc((size_t)2 * NND * PS * 4);  // 38.5 MB
  int* hist  = (int*)alloc((size_t)(16 * HB + 1) * 4);
  int* hist2 = (int*)alloc((size_t)(16 * NSUB * K2) * 4);

  // dropout keys: fold_in(key(42), d) = threefry([0,42],[0,d]); d in {0,1,3}
  unsigned kt0a, kt0b, ks0a, ks0b, ks1a, ks1b;
  tf2x32(0u, 42u, 0u, 0u, kt0a, kt0b);   // layer0 new_t
  tf2x32(0u, 42u, 0u, 1u, ks0a, ks0b);   // layer0 new_s
  tf2x32(0u, 42u, 0u, 3u, ks1a, ks1b);   // layer1 new_s

  const int CB = NN * DD / 8 / 256;          // 6250

  // prep work
  k_cvt2<<<2 * CB, 256, 0, stream>>>(x_src, x_tgt, Xs, Xt, NN * DD / 8);
  k_prep<<<52, 256, 0, stream>>>(Wl_tgt, Wr_tgt, Wl_src, Wr_src, W_o,
                                 Wsw0, Wsw1, Wsw2, Wswo);

  // two-level radix partition + LDS-sort fill (no memsets needed: every
  // hist/hist2/deg/csr entry is fully written by the pipeline)
  k_hist<<<HB, 256, 0, stream>>>(e_dst, r_dst, hist);
  k_scanA<<<1, 256, 0, stream>>>(hist);
  k_scatter1<<<HB, 256, 0, stream>>>(e_src, e_dst, r_src, r_dst, hist, stage1);
  k_hist2<<<16 * K2, 256, 0, stream>>>(stage1, hist, hist2);
  k_scanB<<<1, 256, 0, stream>>>(hist2);
  k_scatter2<<<16 * K2, 256, 0, stream>>>(stage1, hist, hist2, stage2);
  k_fill3<<<2048, 256, 0, stream>>>(stage2, hist2, deg, csr);

  const int GB = (NN + 63) / 64;    // 1563
  const int AB = NN / 4;            // 25000
  const int*   deg_t = deg;
  const int*   deg_s = deg + NND;
  const int*   csr_e = csr;
  const int*   csr_r = csr + (size_t)NND * PS;
  // layer 0, target side: new_t = f(mean(x_src), x_tgt)
  k_agg<<<AB, 256, 0, stream>>>(Xs, deg_t, csr_e, A);
  k_fused<<<GB, 256, 0, stream>>>(A, Xt, Wsw0, bl_tgt, B, kt0a, kt0b);
  // layer 0, source side: new_s = f(mean(x_tgt), x_src)
  k_agg<<<AB, 256, 0, stream>>>(Xt, deg_s, csr_r, A);
  k_fused<<<GB, 256, 0, stream>>>(A, Xs, Wsw1, bl_src, C, ks0a, ks0b);
  // layer 1, source side only (layer-1 target output is dead)
  k_agg<<<AB, 256, 0, stream>>>(B, deg_s, csr_r, A);
  k_fused<<<GB, 256, 0, stream>>>(A, C, Wsw2, bl_src + 128, B, ks1a, ks1b);
  // out = h_s1 @ W_out + b_out
  k_out<<<GB, 256, 0, stream>>>(B, Wswo, b_o, out);
}

// Round 9
// 578.770 us; speedup vs baseline: 2.2875x; 1.0193x over previous
//
#include <hip/hip_runtime.h>
#include <stdint.h>

#define NN 100000     // N_SRC == N_TGT
#define NE 1600000
#define DD 128
#define HB 1024       // hist/scatter1 grid
#define G8 12544      // nodes per top bucket = 128 * 98
#define SUBN 98       // nodes per sub-bucket
#define NSUB 128      // sub-buckets per top bucket
#define NND 100352    // padded node count = 8 * G8
#define K2 16         // chunks per top bucket (hist2/scatter2)
#define RCAP 2304     // record cap per sub-bucket (mean 1568, sd ~40)

typedef unsigned short u16;
typedef short short8 __attribute__((ext_vector_type(8)));
typedef float floatx4 __attribute__((ext_vector_type(4)));
typedef int intx4 __attribute__((ext_vector_type(4)));

// ===================== helpers =====================
__device__ static inline u16 f2bf(float f){
  unsigned u = __float_as_uint(f);
  unsigned r = u + 0x7FFFu + ((u >> 16) & 1u);   // RNE
  return (u16)(r >> 16);
}

// ===================== threefry2x32 (JAX-compatible) =====================
__host__ __device__ static inline unsigned rotl32(unsigned x, int r){
  return (x << r) | (x >> (32 - r));
}

__host__ __device__ static inline void tf2x32(unsigned k0, unsigned k1,
                                              unsigned c0, unsigned c1,
                                              unsigned &o0, unsigned &o1)
{
  const unsigned ks2 = k0 ^ k1 ^ 0x1BD11BDAu;
  unsigned x0 = c0 + k0, x1 = c1 + k1;
#define TFR(r) { x0 += x1; x1 = rotl32(x1, (r)); x1 ^= x0; }
  TFR(13) TFR(15) TFR(26) TFR(6)   x0 += k1;  x1 += ks2 + 1u;
  TFR(17) TFR(29) TFR(16) TFR(24)  x0 += ks2; x1 += k0 + 2u;
  TFR(13) TFR(15) TFR(26) TFR(6)   x0 += k0;  x1 += k1 + 3u;
  TFR(17) TFR(29) TFR(16) TFR(24)  x0 += k1;  x1 += ks2 + 4u;
  TFR(13) TFR(15) TFR(26) TFR(6)   x0 += ks2; x1 += k0 + 5u;
#undef TFR
  o0 = x0; o1 = x1;
}

__device__ static inline float drop_scale(unsigned k0, unsigned k1, unsigned j)
{
  unsigned o0, o1;
  tf2x32(k0, k1, 0u, j, o0, o1);
  const unsigned bits = o0 ^ o1;
  const float u = __uint_as_float((bits >> 9) | 0x3F800000u) - 1.0f;
  return (u < 0.9f) ? (1.0f / 0.9f) : 0.0f;
}

// ===================== level-1 partition: 16 buckets (dir x 8 ranges) ========
__global__ __launch_bounds__(256) void k_hist(const int* __restrict__ e_dst,
                                              const int* __restrict__ r_dst,
                                              int* __restrict__ hist){
  __shared__ int h[16];
  const int t = threadIdx.x;
  if (t < 16) h[t] = 0;
  __syncthreads();
  const int QT = 2 * (NE / 4);
  for (int i = blockIdx.x * 256 + t; i < QT; i += HB * 256){
    int dir = (i >= NE / 4);
    int qi = dir ? i - NE / 4 : i;
    const int* dp = dir ? r_dst : e_dst;
    intx4 d = __builtin_nontemporal_load((const intx4*)dp + qi);
    int bb = dir << 3;
    atomicAdd(&h[bb + d.x / G8], 1);
    atomicAdd(&h[bb + d.y / G8], 1);
    atomicAdd(&h[bb + d.z / G8], 1);
    atomicAdd(&h[bb + d.w / G8], 1);
  }
  __syncthreads();
  if (t < 16) hist[t * HB + blockIdx.x] = h[t];
}

// Exclusive scan over hist[16*HB] (bucket-major); hist[16*HB] = total.
__global__ __launch_bounds__(256) void k_scanA(int* __restrict__ hist){
  __shared__ int sh[16 * HB];
  __shared__ int tot[256];
  const int t = threadIdx.x;
  const int N = 16 * HB;
  for (int k = t; k < N; k += 256) sh[k] = hist[k];
  __syncthreads();
  int s = 0;
  #pragma unroll 4
  for (int k = 0; k < 64; ++k)
    s += sh[(t >> 4) * HB + (t & 15) + (k << 4)];
  tot[t] = s;
  __syncthreads();
  int v = s;
  for (int off = 1; off < 256; off <<= 1){
    int u = (t >= off) ? tot[t - off] : 0;
    __syncthreads();
    tot[t] += u;
    __syncthreads();
  }
  int run = tot[t] - v;
  for (int k = 0; k < 64; ++k){
    int idx = (t >> 4) * HB + (t & 15) + (k << 4);
    int xv = sh[idx];
    sh[idx] = run;
    run += xv;
  }
  __syncthreads();
  for (int k = t; k < N; k += 256) hist[k] = sh[k];
  if (t == 255) hist[N] = tot[255];   // grand total = 2*NE
}

// Scatter into 16 bucket-contiguous regions. Record = (node_local<<17)|src.
__global__ __launch_bounds__(256) void k_scatter1(const int* __restrict__ e_src,
                                                  const int* __restrict__ e_dst,
                                                  const int* __restrict__ r_src,
                                                  const int* __restrict__ r_dst,
                                                  const int* __restrict__ base,
                                                  unsigned* __restrict__ stage){
  __shared__ int cur[16];
  const int t = threadIdx.x;
  if (t < 16) cur[t] = base[t * HB + blockIdx.x];
  __syncthreads();
  const int QT = 2 * (NE / 4);
  for (int i = blockIdx.x * 256 + t; i < QT; i += HB * 256){
    int dir = (i >= NE / 4);
    int qi = dir ? i - NE / 4 : i;
    const int* dp = dir ? r_dst : e_dst;
    const int* sp = dir ? r_src : e_src;
    intx4 d = __builtin_nontemporal_load((const intx4*)dp + qi);
    intx4 sv = __builtin_nontemporal_load((const intx4*)sp + qi);
    int bb = dir << 3;
    int g, p;
    g = d.x / G8; p = atomicAdd(&cur[bb + g], 1);
    stage[p] = (unsigned)sv.x | ((unsigned)(d.x - g * G8) << 17);
    g = d.y / G8; p = atomicAdd(&cur[bb + g], 1);
    stage[p] = (unsigned)sv.y | ((unsigned)(d.y - g * G8) << 17);
    g = d.z / G8; p = atomicAdd(&cur[bb + g], 1);
    stage[p] = (unsigned)sv.z | ((unsigned)(d.z - g * G8) << 17);
    g = d.w / G8; p = atomicAdd(&cur[bb + g], 1);
    stage[p] = (unsigned)sv.w | ((unsigned)(d.w - g * G8) << 17);
  }
}

// ===================== level-2 partition: 128 sub-buckets per bucket =========
__global__ __launch_bounds__(256) void k_hist2(const unsigned* __restrict__ stage,
                                               const int* __restrict__ base,
                                               int* __restrict__ hist2){
  __shared__ int h2[NSUB];
  const int b16 = blockIdx.x / K2, k = blockIdx.x % K2;
  const int t = threadIdx.x;
  if (t < NSUB) h2[t] = 0;
  __syncthreads();
  const int beg = base[b16 * HB];
  const int end = base[(b16 + 1) * HB];
  for (int i = beg + k * 256 + t; i < end; i += K2 * 256){
    unsigned p = stage[i];
    atomicAdd(&h2[(int)(p >> 17) / SUBN], 1);
  }
  __syncthreads();
  if (t < NSUB) hist2[(b16 * NSUB + t) * K2 + k] = h2[t];
}

// Ordered exclusive scan over hist2[32768] (one block).
__global__ __launch_bounds__(256) void k_scanB(int* __restrict__ hist2){
  __shared__ int sh[16 * NSUB * K2];   // 128 KB
  __shared__ int tot[256];
  const int t = threadIdx.x;
  const int N = 16 * NSUB * K2;
  for (int k = t; k < N; k += 256) sh[k] = hist2[k];
  __syncthreads();
  int s = 0;
  for (int j = 0; j < 128; ++j) s += sh[t * 128 + j];
  tot[t] = s;
  __syncthreads();
  int v = s;
  for (int off = 1; off < 256; off <<= 1){
    int u = (t >= off) ? tot[t - off] : 0;
    __syncthreads();
    tot[t] += u;
    __syncthreads();
  }
  int run = tot[t] - v;
  for (int j = 0; j < 128; ++j){
    int xv = sh[t * 128 + j];
    sh[t * 128 + j] = run;
    run += xv;
  }
  __syncthreads();
  for (int k = t; k < N; k += 256) hist2[k] = sh[k];
}

// Scatter bucket -> sub-bucket-contiguous stage2.
__global__ __launch_bounds__(256) void k_scatter2(const unsigned* __restrict__ stage,
                                                  const int* __restrict__ base,
                                                  const int* __restrict__ h2s,
                                                  unsigned* __restrict__ stage2){
  __shared__ int cur[NSUB];
  const int b16 = blockIdx.x / K2, k = blockIdx.x % K2;
  const int t = threadIdx.x;
  if (t < NSUB) cur[t] = h2s[(b16 * NSUB + t) * K2 + k];
  __syncthreads();
  const int beg = base[b16 * HB];
  const int end = base[(b16 + 1) * HB];
  for (int i = beg + k * 256 + t; i < end; i += K2 * 256){
    unsigned p = stage[i];
    int pos = atomicAdd(&cur[(int)(p >> 17) / SUBN], 1);
    stage2[pos] = p;
  }
}

// ===================== LDS counting-sort -> COMPACT csr + ptr ===============
// One block per sub-bucket (2048). Sort records by node in LDS, write them
// back densely (coalesced, 12.8 MB total) + per-node absolute offsets.
// Global order (dir, range, sub, node) == node-sorted per dir -> ptr monotone.
__global__ __launch_bounds__(256) void k_fill4(const unsigned* __restrict__ stage2,
                                               const int* __restrict__ h2s,
                                               int* __restrict__ ptr,
                                               int* __restrict__ csr){
  __shared__ unsigned rec[RCAP];
  __shared__ unsigned srt[RCAP];
  __shared__ int ldeg[SUBN], lptr[SUBN], lcur[SUBN];
  const int sb = blockIdx.x;              // 0..2047
  const int b16 = sb >> 7, sub = sb & 127;
  const int dir = b16 >> 3, g = b16 & 7;
  const int t = threadIdx.x;
  const int beg = h2s[sb * K2];
  const int end = (sb == 2047) ? 2 * NE : h2s[(sb + 1) * K2];
  int n = end - beg;
  if (n > RCAP) n = RCAP;
  for (int i = t; i < n; i += 256) rec[i] = stage2[beg + i];
  if (t < SUBN) ldeg[t] = 0;
  __syncthreads();
  const int nl0 = sub * SUBN;
  for (int i = t; i < n; i += 256)
    atomicAdd(&ldeg[(int)(rec[i] >> 17) - nl0], 1);
  __syncthreads();
  if (t == 0){
    int run = 0;
    for (int s = 0; s < SUBN; ++s){ lptr[s] = run; lcur[s] = run; run += ldeg[s]; }
  }
  __syncthreads();
  for (int i = t; i < n; i += 256){
    int rl = (int)(rec[i] >> 17) - nl0;
    int pos = atomicAdd(&lcur[rl], 1);
    srt[pos] = rec[i] & 0x1FFFFu;
  }
  __syncthreads();
  const int node0 = g * G8 + nl0;
  if (t < SUBN) ptr[dir * NND + node0 + t] = beg + lptr[t];
  if (sb == 2047 && t == 0) ptr[2 * NND] = 2 * NE;
  for (int i = t; i < n; i += 256) csr[beg + i] = (int)srt[i];
}

// ===================== fp32 -> bf16 convert (both inputs) ====================
__global__ __launch_bounds__(256) void k_cvt2(const float* __restrict__ ina,
                                              const float* __restrict__ inb,
                                              u16* __restrict__ oa,
                                              u16* __restrict__ ob, int n8){
  int i = blockIdx.x * 256 + threadIdx.x;
  const float* in = ina; u16* out = oa;
  if (i >= n8){ i -= n8; in = inb; out = ob; }
  floatx4 a = __builtin_nontemporal_load((const floatx4*)in + (size_t)i * 2);
  floatx4 b = __builtin_nontemporal_load((const floatx4*)in + (size_t)i * 2 + 1);
  u16 v[8] = { f2bf(a[0]), f2bf(a[1]), f2bf(a[2]), f2bf(a[3]),
               f2bf(b[0]), f2bf(b[1]), f2bf(b[2]), f2bf(b[3]) };
  *(uint4*)(out + (size_t)i * 8) = *(const uint4*)v;
}

// ===================== weight pre-swizzle (all weights, one kernel) ==========
__global__ __launch_bounds__(256) void k_prep(const float* __restrict__ Wl_tgt,
    const float* __restrict__ Wr_tgt, const float* __restrict__ Wl_src,
    const float* __restrict__ Wr_src, const float* __restrict__ Wo,
    u16* __restrict__ Wsw0, u16* __restrict__ Wsw1, u16* __restrict__ Wsw2,
    u16* __restrict__ Wswo){
  int b = blockIdx.x;
  if (b < 48){
    const float *Wl, *Wr; u16* dst;
    if (b < 16){ Wl = Wl_tgt; Wr = Wr_tgt; dst = Wsw0; }
    else if (b < 32){ Wl = Wl_src; Wr = Wr_src; dst = Wsw1; b -= 16; }
    else { Wl = Wl_src + 16384; Wr = Wr_src + 16384; dst = Wsw2; b -= 32; }
    int idx = b * 256 + threadIdx.x;
    int lane = idx & 63, tile = idx >> 6;
    int kt = tile >> 3, nt = tile & 7;
    int n = nt * 16 + (lane & 15);
    int kb = kt * 32 + (lane >> 4) * 8;
    u16 v[8];
    #pragma unroll
    for (int j = 0; j < 8; ++j){
      int k = kb + j;
      float w = (k < 128) ? Wl[(size_t)k * 128 + n] : Wr[(size_t)(k - 128) * 128 + n];
      v[j] = f2bf(w);
    }
    *(uint4*)(dst + (size_t)idx * 8) = *(const uint4*)v;
  } else {
    int idx = (b - 48) * 256 + threadIdx.x;
    int lane = idx & 63, tile = idx >> 6;
    int kt = tile >> 2, nt = tile & 3;
    int n = nt * 16 + (lane & 15);
    int kb = kt * 32 + (lane >> 4) * 8;
    u16 v[8];
    #pragma unroll
    for (int j = 0; j < 8; ++j)
      v[j] = f2bf(Wo[(size_t)(kb + j) * 64 + n]);
    *(uint4*)(Wswo + (size_t)idx * 8) = *(const uint4*)v;
  }
}

// ===================== mean aggregation body =================================
// 1 wave/row; 4 lane-groups of 16: one gather instr = one full 256 B row.
__device__ static inline void agg_body(const u16* __restrict__ x,
                                       const int* __restrict__ pd,
                                       const int* __restrict__ csr,
                                       u16* __restrict__ out, int blk){
  const int row = blk * 4 + (threadIdx.x >> 6);
  const int lane = threadIdx.x & 63;
  const int sub = lane >> 4, l4 = lane & 15;
  const int beg = pd[row], end = pd[row + 1];
  const int cnt = end - beg;
  float a[8] = {0.f,0.f,0.f,0.f,0.f,0.f,0.f,0.f};
  int e = 0;
  for (; e + 7 < cnt; e += 8){
    int s0 = csr[beg + e + sub];
    int s1 = csr[beg + e + 4 + sub];
    uint4 v0 = *(const uint4*)(x + (size_t)s0 * DD + l4 * 8);
    uint4 v1 = *(const uint4*)(x + (size_t)s1 * DD + l4 * 8);
    a[0] += __uint_as_float(v0.x << 16); a[1] += __uint_as_float(v0.x & 0xFFFF0000u);
    a[2] += __uint_as_float(v0.y << 16); a[3] += __uint_as_float(v0.y & 0xFFFF0000u);
    a[4] += __uint_as_float(v0.z << 16); a[5] += __uint_as_float(v0.z & 0xFFFF0000u);
    a[6] += __uint_as_float(v0.w << 16); a[7] += __uint_as_float(v0.w & 0xFFFF0000u);
    a[0] += __uint_as_float(v1.x << 16); a[1] += __uint_as_float(v1.x & 0xFFFF0000u);
    a[2] += __uint_as_float(v1.y << 16); a[3] += __uint_as_float(v1.y & 0xFFFF0000u);
    a[4] += __uint_as_float(v1.z << 16); a[5] += __uint_as_float(v1.z & 0xFFFF0000u);
    a[6] += __uint_as_float(v1.w << 16); a[7] += __uint_as_float(v1.w & 0xFFFF0000u);
  }
  for (; e + 3 < cnt; e += 4){
    int s0 = csr[beg + e + sub];
    uint4 v0 = *(const uint4*)(x + (size_t)s0 * DD + l4 * 8);
    a[0] += __uint_as_float(v0.x << 16); a[1] += __uint_as_float(v0.x & 0xFFFF0000u);
    a[2] += __uint_as_float(v0.y << 16); a[3] += __uint_as_float(v0.y & 0xFFFF0000u);
    a[4] += __uint_as_float(v0.z << 16); a[5] += __uint_as_float(v0.z & 0xFFFF0000u);
    a[6] += __uint_as_float(v0.w << 16); a[7] += __uint_as_float(v0.w & 0xFFFF0000u);
  }
  if (e + sub < cnt){
    int s0 = csr[beg + e + sub];
    uint4 v0 = *(const uint4*)(x + (size_t)s0 * DD + l4 * 8);
    a[0] += __uint_as_float(v0.x << 16); a[1] += __uint_as_float(v0.x & 0xFFFF0000u);
    a[2] += __uint_as_float(v0.y << 16); a[3] += __uint_as_float(v0.y & 0xFFFF0000u);
    a[4] += __uint_as_float(v0.z << 16); a[5] += __uint_as_float(v0.z & 0xFFFF0000u);
    a[6] += __uint_as_float(v0.w << 16); a[7] += __uint_as_float(v0.w & 0xFFFF0000u);
  }
  #pragma unroll
  for (int i = 0; i < 8; ++i){
    a[i] += __shfl_xor(a[i], 16);
    a[i] += __shfl_xor(a[i], 32);
  }
  const float inv = (cnt > 0) ? (1.0f / (float)cnt) : 1.0f;
  if (sub == 0){
    unsigned pk[4];
    #pragma unroll
    for (int i = 0; i < 4; ++i)
      pk[i] = (unsigned)f2bf(a[2*i] * inv) | ((unsigned)f2bf(a[2*i+1] * inv) << 16);
    *(uint4*)(out + (size_t)row * DD + l4 * 8) = make_uint4(pk[0], pk[1], pk[2], pk[3]);
  }
}

// dual-direction agg (layer 0): first AB blocks = dir0, rest = dir1
__global__ __launch_bounds__(256) void k_aggD(const u16* __restrict__ x0,
    const u16* __restrict__ x1, const int* __restrict__ ptr,
    const int* __restrict__ csr, u16* __restrict__ o0, u16* __restrict__ o1){
  int b = blockIdx.x;
  if (b < NN / 4) agg_body(x0, ptr, csr, o0, b);
  else            agg_body(x1, ptr + NND, csr, o1, b - NN / 4);
}

// single-direction agg (layer 1, dir1)
__global__ __launch_bounds__(256) void k_agg1(const u16* __restrict__ x,
    const int* __restrict__ ptr, const int* __restrict__ csr,
    u16* __restrict__ out){
  agg_body(x, ptr + NND, csr, out, blockIdx.x);
}

// ===================== fused layer GEMM body =================================
__device__ static inline void fused_body(const u16* __restrict__ Am,
    const u16* __restrict__ X, const u16* __restrict__ Wsw,
    const float* __restrict__ bias, u16* __restrict__ outH,
    unsigned key0, unsigned key1, int blk)
{
  const int wave = threadIdx.x >> 6, lane = threadIdx.x & 63;
  const int quad = lane >> 4, col0 = lane & 15;
  const int row0 = blk * 64 + wave * 16;
  int m = row0 + col0;
  if (m >= NN) m = NN - 1;

  floatx4 acc[8];
  #pragma unroll
  for (int i = 0; i < 8; ++i) acc[i] = (floatx4)0.f;

  #pragma unroll
  for (int kt = 0; kt < 8; ++kt){
    const int k = kt * 32 + quad * 8;
    const u16* ap = (k < 128) ? (Am + (size_t)m * 128 + k)
                              : (X  + (size_t)m * 128 + (k - 128));
    short8 a = __builtin_nontemporal_load((const short8*)ap);
    #pragma unroll
    for (int nt = 0; nt < 8; ++nt){
      short8 b = *(const short8*)(Wsw + (size_t)(((kt * 8 + nt) * 64 + lane) * 8));
      acc[nt] = __builtin_amdgcn_mfma_f32_16x16x32_bf16(a, b, acc[nt], 0, 0, 0);
    }
  }

  #pragma unroll
  for (int nt = 0; nt < 8; ++nt){
    const int col = nt * 16 + col0;
    const float bj = bias[col];
    #pragma unroll
    for (int rg = 0; rg < 4; ++rg){
      const int r = row0 + quad * 4 + rg;
      if (r < NN){
        float h = acc[nt][rg] + bj;
        h = (h >= 0.f) ? h : 0.01f * h;
        unsigned j = (unsigned)r * 128u + (unsigned)col;
        h *= drop_scale(key0, key1, j);
        outH[(size_t)r * 128 + col] = f2bf(h);
      }
    }
  }
}

#define GB ((NN + 63) / 64)   // 1563

// dual fused GEMM (layer 0, both sides in one launch)
__global__ __launch_bounds__(256) void k_fusedD(
    const u16* __restrict__ A0, const u16* __restrict__ X0,
    const u16* __restrict__ W0, const float* __restrict__ b0,
    u16* __restrict__ o0, unsigned k00, unsigned k01,
    const u16* __restrict__ A1, const u16* __restrict__ X1,
    const u16* __restrict__ W1, const float* __restrict__ b1,
    u16* __restrict__ o1, unsigned k10, unsigned k11)
{
  int b = blockIdx.x;
  if (b < GB) fused_body(A0, X0, W0, b0, o0, k00, k01, b);
  else        fused_body(A1, X1, W1, b1, o1, k10, k11, b - GB);
}

__global__ __launch_bounds__(256) void k_fused(const u16* __restrict__ Am,
    const u16* __restrict__ X, const u16* __restrict__ Wsw,
    const float* __restrict__ bias, u16* __restrict__ outH,
    unsigned key0, unsigned key1)
{
  fused_body(Am, X, Wsw, bias, outH, key0, key1, blockIdx.x);
}

// ===================== output GEMM via MFMA (fp32 out) =======================
__global__ __launch_bounds__(256) void k_out(const u16* __restrict__ H,
    const u16* __restrict__ Wsw, const float* __restrict__ bias,
    float* __restrict__ out)
{
  const int wave = threadIdx.x >> 6, lane = threadIdx.x & 63;
  const int quad = lane >> 4, col0 = lane & 15;
  const int row0 = blockIdx.x * 64 + wave * 16;
  int m = row0 + col0;
  if (m >= NN) m = NN - 1;

  floatx4 acc[4];
  #pragma unroll
  for (int i = 0; i < 4; ++i) acc[i] = (floatx4)0.f;

  #pragma unroll
  for (int kt = 0; kt < 4; ++kt){
    short8 a = __builtin_nontemporal_load(
        (const short8*)(H + (size_t)m * 128 + kt * 32 + quad * 8));
    #pragma unroll
    for (int nt = 0; nt < 4; ++nt){
      short8 b = *(const short8*)(Wsw + (size_t)(((kt * 4 + nt) * 64 + lane) * 8));
      acc[nt] = __builtin_amdgcn_mfma_f32_16x16x32_bf16(a, b, acc[nt], 0, 0, 0);
    }
  }

  #pragma unroll
  for (int nt = 0; nt < 4; ++nt){
    const int col = nt * 16 + col0;
    const float bj = bias[col];
    #pragma unroll
    for (int rg = 0; rg < 4; ++rg){
      const int r = row0 + quad * 4 + rg;
      if (r < NN)
        out[(size_t)r * 64 + col] = acc[nt][rg] + bj;
    }
  }
}

// ===================== launch =====================
extern "C" void kernel_launch(void* const* d_in, const int* in_sizes, int n_in,
                              void* d_out, int out_size, void* d_ws, size_t ws_size,
                              hipStream_t stream)
{
  const float* x_src  = (const float*)d_in[0];
  const float* x_tgt  = (const float*)d_in[1];
  const float* Wl_tgt = (const float*)d_in[2];
  const float* bl_tgt = (const float*)d_in[3];
  const float* Wr_tgt = (const float*)d_in[4];
  const float* Wl_src = (const float*)d_in[5];
  const float* bl_src = (const float*)d_in[6];
  const float* Wr_src = (const float*)d_in[7];
  const float* W_o    = (const float*)d_in[8];
  const float* b_o    = (const float*)d_in[9];
  const int*   e_src  = (const int*)d_in[10];
  const int*   e_dst  = (const int*)d_in[11];
  const int*   r_src  = (const int*)d_in[12];
  const int*   r_dst  = (const int*)d_in[13];
  float* out = (float*)d_out;
  (void)in_sizes; (void)n_in; (void)out_size; (void)ws_size;

  char* ws = (char*)d_ws;
  size_t off = 0;
  auto alloc = [&](size_t bytes) -> char* {
    char* p = ws + off; off += (bytes + 255) & ~(size_t)255; return p;
  };
  // stage1+stage2 (25.6 MB, contiguous) die after k_fill4; A_t aliases them.
  unsigned* stage1 = (unsigned*)alloc((size_t)2 * NE * 4);
  unsigned* stage2 = (unsigned*)alloc((size_t)2 * NE * 4);
  u16* A_t  = (u16*)stage1;                        // 25.6 MB alias
  u16* A_s  = (u16*)alloc((size_t)NN * DD * 2);
  u16* Xs   = (u16*)alloc((size_t)NN * DD * 2);
  u16* Xt   = (u16*)alloc((size_t)NN * DD * 2);
  u16* B    = (u16*)alloc((size_t)NN * DD * 2);    // h_t(l0), then h_s(l1)
  u16* C    = (u16*)alloc((size_t)NN * DD * 2);    // h_s(l0)
  u16* Wsw0 = (u16*)alloc(256 * 128 * 2);
  u16* Wsw1 = (u16*)alloc(256 * 128 * 2);
  u16* Wsw2 = (u16*)alloc(256 * 128 * 2);
  u16* Wswo = (u16*)alloc(128 * 64 * 2);
  int* csr  = (int*)alloc((size_t)2 * NE * 4);     // compact, node-sorted
  int* ptr  = (int*)alloc((size_t)(2 * NND + 1) * 4);
  int* hist  = (int*)alloc((size_t)(16 * HB + 1) * 4);
  int* hist2 = (int*)alloc((size_t)(16 * NSUB * K2) * 4);

  // dropout keys: fold_in(key(42), d) = threefry([0,42],[0,d]); d in {0,1,3}
  unsigned kt0a, kt0b, ks0a, ks0b, ks1a, ks1b;
  tf2x32(0u, 42u, 0u, 0u, kt0a, kt0b);   // layer0 new_t
  tf2x32(0u, 42u, 0u, 1u, ks0a, ks0b);   // layer0 new_s
  tf2x32(0u, 42u, 0u, 3u, ks1a, ks1b);   // layer1 new_s

  const int CB = NN * DD / 8 / 256;          // 6250

  // prep work
  k_cvt2<<<2 * CB, 256, 0, stream>>>(x_src, x_tgt, Xs, Xt, NN * DD / 8);
  k_prep<<<52, 256, 0, stream>>>(Wl_tgt, Wr_tgt, Wl_src, Wr_src, W_o,
                                 Wsw0, Wsw1, Wsw2, Wswo);

  // two-level radix partition + LDS-sort -> compact csr + ptr
  k_hist<<<HB, 256, 0, stream>>>(e_dst, r_dst, hist);
  k_scanA<<<1, 256, 0, stream>>>(hist);
  k_scatter1<<<HB, 256, 0, stream>>>(e_src, e_dst, r_src, r_dst, hist, stage1);
  k_hist2<<<16 * K2, 256, 0, stream>>>(stage1, hist, hist2);
  k_scanB<<<1, 256, 0, stream>>>(hist2);
  k_scatter2<<<16 * K2, 256, 0, stream>>>(stage1, hist, hist2, stage2);
  k_fill4<<<2048, 256, 0, stream>>>(stage2, hist2, ptr, csr);

  const int AB = NN / 4;            // 25000
  // layer 0: both directions in single launches
  k_aggD<<<2 * AB, 256, 0, stream>>>(Xs, Xt, ptr, csr, A_t, A_s);
  k_fusedD<<<2 * GB, 256, 0, stream>>>(A_t, Xt, Wsw0, bl_tgt, B, kt0a, kt0b,
                                       A_s, Xs, Wsw1, bl_src, C, ks0a, ks0b);
  // layer 1, source side only (layer-1 target output is dead)
  k_agg1<<<AB, 256, 0, stream>>>(B, ptr, csr, A_t);
  k_fused<<<GB, 256, 0, stream>>>(A_t, C, Wsw2, bl_src + 128, B, ks1a, ks1b);
  // out = h_s1 @ W_out + b_out
  k_out<<<GB, 256, 0, stream>>>(B, Wswo, b_o, out);
}